// Round 3
// baseline (546.314 us; speedup 1.0000x reference)
//
#include <hip/hip_runtime.h>

#define BB   4
#define CC   256
#define NPIX 4096
#define AST2 40    // mfma-core LDS row stride (shorts), 80 B, 16B-aligned
#define YST  72    // pv LDS row stride (shorts), 144 B, 16B-aligned

typedef __attribute__((ext_vector_type(8)))  short bf16x8;
typedef __attribute__((ext_vector_type(8)))  _Float16 f16x8;
typedef __attribute__((ext_vector_type(4)))  short short4v;
typedef __attribute__((ext_vector_type(16))) float f32x16;

__device__ __forceinline__ short f2h(float f) {
    _Float16 h = (_Float16)f;           // v_cvt_f16_f32 (RNE)
    return __builtin_bit_cast(short, h);
}
__device__ __forceinline__ int cdrow(int r, int l5) {
    return (r & 3) + 8 * (r >> 2) + 4 * l5;   // verified m74/m101 C/D row map
}

// ---------------------------------------------------------------------------
// Single-fp16 MFMA core: 128x128 tile, K=256, register-prefetch pipelined.
// 20 KB LDS.
// ---------------------------------------------------------------------------
__device__ __forceinline__ void mfma_core_f16(
    const short* __restrict__ A, const short* __restrict__ B, f32x16 acc[2][2])
{
    __shared__ short LA[128 * AST2], LB[128 * AST2];
    const int t = threadIdx.x;
    const int lane = t & 63, w = t >> 6;
    const int l31 = lane & 31, l5 = lane >> 5;
    const int nq = (w & 1) * 64, mq = (w >> 1) * 64;
    const int sr = t >> 1;
    const int sk = (t & 1) * 16;
    const size_t gs = (size_t)sr * 256 + sk;
    const int ls = sr * AST2 + sk;

    bf16x8 rA0 = *(const bf16x8*)(A + gs);
    bf16x8 rA1 = *(const bf16x8*)(A + gs + 8);
    bf16x8 rB0 = *(const bf16x8*)(B + gs);
    bf16x8 rB1 = *(const bf16x8*)(B + gs + 8);

    for (int k0 = 0; k0 < 256; k0 += 32) {
        __syncthreads();
        *(bf16x8*)&LA[ls]     = rA0;
        *(bf16x8*)&LA[ls + 8] = rA1;
        *(bf16x8*)&LB[ls]     = rB0;
        *(bf16x8*)&LB[ls + 8] = rB1;
        __syncthreads();
        if (k0 + 32 < 256) {
            size_t g = gs + k0 + 32;
            rA0 = *(const bf16x8*)(A + g);
            rA1 = *(const bf16x8*)(A + g + 8);
            rB0 = *(const bf16x8*)(B + g);
            rB1 = *(const bf16x8*)(B + g + 8);
        }
#pragma unroll
        for (int ks = 0; ks < 2; ks++) {
            f16x8 a[2], b[2];
#pragma unroll
            for (int s = 0; s < 2; s++) {
                a[s] = *(const f16x8*)&LA[(nq + s * 32 + l31) * AST2 + ks * 16 + l5 * 8];
                b[s] = *(const f16x8*)&LB[(mq + s * 32 + l31) * AST2 + ks * 16 + l5 * 8];
            }
#pragma unroll
            for (int s = 0; s < 2; s++)
#pragma unroll
                for (int u = 0; u < 2; u++)
                    acc[s][u] = __builtin_amdgcn_mfma_f32_32x32x16_f16(a[s], b[u], acc[s][u], 0, 0, 0);
        }
    }
}

// ---------------- pack kernels ----------------

// all 5 weights fp32 -> fp16, same layout. grid (64, 5)
__global__ __launch_bounds__(256) void pack_w5(
    const float* __restrict__ w0, const float* __restrict__ w1,
    const float* __restrict__ w2, const float* __restrict__ w3,
    const float* __restrict__ w4, short* __restrict__ wall)
{
    int which = blockIdx.y;
    const float* w = which == 0 ? w0 : which == 1 ? w1 : which == 2 ? w2
                   : which == 3 ? w3 : w4;
    int idx = blockIdx.x * 1024 + threadIdx.x * 4;
    float4 v = *(const float4*)(w + idx);
    short4v h;
    h.x = f2h(v.x); h.y = f2h(v.y); h.z = f2h(v.z); h.w = f2h(v.w);
    *(short4v*)(wall + which * 65536 + idx) = h;
}

// transpose fp32 [c][n] -> single fp16 [n][c]. grid (128,8,4)
__global__ __launch_bounds__(256) void pack_t_f16(
    const float* __restrict__ in, short* __restrict__ o16)
{
    __shared__ short T[32][36];
    const int b  = blockIdx.z;
    const int n0 = blockIdx.x * 32;
    const int c0 = blockIdx.y * 32;
    const float* src = in + (size_t)b * CC * NPIX;
    const int t = threadIdx.x;
    const int r = t >> 3, q = t & 7;
    float4 v = *(const float4*)(src + (size_t)(c0 + r) * NPIX + n0 + q * 4);
    T[q * 4 + 0][r] = f2h(v.x);
    T[q * 4 + 1][r] = f2h(v.y);
    T[q * 4 + 2][r] = f2h(v.z);
    T[q * 4 + 3][r] = f2h(v.w);
    __syncthreads();
    short4v o;
    o.x = T[r][q * 4 + 0];
    o.y = T[r][q * 4 + 1];
    o.z = T[r][q * 4 + 2];
    o.w = T[r][q * 4 + 3];
    size_t oo = (size_t)b * CC * NPIX + (size_t)(n0 + r) * 256 + c0 + q * 4;
    *(short4v*)(o16 + oo) = o;
}

// transpose fp16 [256][4096] -> fp16 [4096][256]. grid (128,8,4)
__global__ __launch_bounds__(256) void tr16_cn(
    const short* __restrict__ in, short* __restrict__ outp)
{
    __shared__ short T[32][33];
    const int b  = blockIdx.z;
    const int n0 = blockIdx.x * 32;
    const int c0 = blockIdx.y * 32;
    const short* src = in + (size_t)b * CC * NPIX;
    short* dst = outp + (size_t)b * CC * NPIX;
    const int t = threadIdx.x;
    const int r = t >> 3, q = t & 7;
    short4v v = *(const short4v*)(src + (size_t)(c0 + r) * NPIX + n0 + q * 4);
    T[q * 4 + 0][r] = v.x;
    T[q * 4 + 1][r] = v.y;
    T[q * 4 + 2][r] = v.z;
    T[q * 4 + 3][r] = v.w;
    __syncthreads();
    short4v o;
    o.x = T[r][q * 4 + 0];
    o.y = T[r][q * 4 + 1];
    o.z = T[r][q * 4 + 2];
    o.w = T[r][q * 4 + 3];
    *(short4v*)(dst + (size_t)(n0 + r) * 256 + c0 + q * 4) = o;
}

// Vt[c][m] = x3f.flat[m*256+c] (already fp16). grid (128,8,4)
__global__ __launch_bounds__(256) void packVt_bf(
    const short* __restrict__ x3f, short* __restrict__ Vt)
{
    __shared__ short T[32][33];
    const int b  = blockIdx.z;
    const int m0 = blockIdx.x * 32;
    const int c0 = blockIdx.y * 32;
    const short* in = x3f + (size_t)b * CC * NPIX;
    short* out = Vt + (size_t)b * CC * NPIX;
    const int t = threadIdx.x;
    const int r = t >> 3, q = t & 7;
    short4v v = *(const short4v*)(in + (size_t)(m0 + r) * CC + c0 + q * 4);
    T[q * 4 + 0][r] = v.x;
    T[q * 4 + 1][r] = v.y;
    T[q * 4 + 2][r] = v.z;
    T[q * 4 + 3][r] = v.w;
    __syncthreads();
    short4v o;
    o.x = T[r][q * 4 + 0];
    o.y = T[r][q * 4 + 1];
    o.z = T[r][q * 4 + 2];
    o.w = T[r][q * 4 + 3];
    *(short4v*)(out + (size_t)(c0 + r) * NPIX + m0 + q * 4) = o;
}

// ---------------- GEMM kernels ----------------

// proj. grid (32, 2, 12). p=0 -> x1, p=1 -> x2, p=2 -> x3; all fp16 [c][n].
__global__ __launch_bounds__(256) void proj_mfma(
    const short* __restrict__ wpf, const short* __restrict__ xtf,
    const float* __restrict__ b_teta, const float* __restrict__ b_fi,
    const float* __restrict__ b_gi,
    short* __restrict__ x1f, short* __restrict__ x2f, short* __restrict__ x3f)
{
    const int z = blockIdx.z, p = z >> 2, b = z & 3;
    const int n0 = blockIdx.x * 128, c0 = blockIdx.y * 128;
    const size_t CN = (size_t)CC * NPIX;
    const short* Ah = wpf + p * 65536 + c0 * 256;
    const short* Bh = xtf + (size_t)b * CN + (size_t)n0 * 256;
    const float* bias = p == 0 ? b_teta : p == 1 ? b_fi : b_gi;
    short* dst = p == 0 ? x1f : p == 1 ? x2f : x3f;

    f32x16 acc[2][2] = {};
    mfma_core_f16(Ah, Bh, acc);

    const int t = threadIdx.x, lane = t & 63, w = t >> 6;
    const int l31 = lane & 31, l5 = lane >> 5;
    const int aq = (w & 1) * 64, bq = (w >> 1) * 64;
#pragma unroll
    for (int s = 0; s < 2; s++)
#pragma unroll
        for (int u = 0; u < 2; u++)
#pragma unroll
            for (int r = 0; r < 16; r++) {
                int c = c0 + aq + s * 32 + cdrow(r, l5);
                int n = n0 + bq + u * 32 + l31;
                float v = acc[s][u][r] + bias[c];
                size_t o = (size_t)b * CN + (size_t)c * NPIX + n;
                dst[o] = f2h(v);
            }
}

// scores + fused column AND row partial stats. grid (32, 32) per batch.
__global__ __launch_bounds__(256) void scores_mfma(
    const short* __restrict__ x1f, const short* __restrict__ x2tf,
    float* __restrict__ S, float* __restrict__ pm, float* __restrict__ pl,
    float* __restrict__ prm, float* __restrict__ plr)
{
    const int m0 = blockIdx.x * 128, n0 = blockIdx.y * 128;
    f32x16 acc[2][2] = {};
    mfma_core_f16(x1f + (size_t)n0 * 256, x2tf + (size_t)m0 * 256, acc);

    const int t = threadIdx.x, lane = t & 63, w = t >> 6;
    const int l31 = lane & 31, l5 = lane >> 5;
    const int aq = (w & 1) * 64, bq = (w >> 1) * 64;
#pragma unroll
    for (int s = 0; s < 2; s++)
#pragma unroll
        for (int u = 0; u < 2; u++)
#pragma unroll
            for (int r = 0; r < 16; r++) {
                int n = n0 + aq + s * 32 + cdrow(r, l5);
                int m = m0 + bq + u * 32 + l31;
                S[(size_t)n * NPIX + m] = acc[s][u][r];
            }

    // column partial stats over this block's 64-row half (member = w&1).
    const int member = w & 1;
#pragma unroll
    for (int u = 0; u < 2; u++) {
        float vmax = -1e30f;
#pragma unroll
        for (int s = 0; s < 2; s++)
#pragma unroll
            for (int r = 0; r < 16; r++) vmax = fmaxf(vmax, acc[s][u][r]);
        float vsum = 0.0f;
#pragma unroll
        for (int s = 0; s < 2; s++)
#pragma unroll
            for (int r = 0; r < 16; r++) vsum += __expf(acc[s][u][r] - vmax);
        // combine with partner lane (lane^32) holding the other 16 rows/stripe
        float vmax2 = __shfl_xor(vmax, 32, 64);
        float vsum2 = __shfl_xor(vsum, 32, 64);
        float mc = fmaxf(vmax, vmax2);
        float sc = vsum * __expf(vmax - mc) + vsum2 * __expf(vmax2 - mc);
        if (l5 == 0) {
            size_t pidx = (size_t)(blockIdx.y * 2 + member) * NPIX + m0 + bq + u * 32 + l31;
            pm[pidx] = mc;
            pl[pidx] = sc;
        }
    }

    // row partial stats over this block's 64-col half (member2 = w>>1).
    // reduce over u (in-thread) + l31 butterfly (stays within l5 half).
    const int member2 = w >> 1;
#pragma unroll
    for (int s = 0; s < 2; s++)
#pragma unroll
        for (int r = 0; r < 16; r++) {
            float vmax = fmaxf(acc[s][0][r], acc[s][1][r]);
#pragma unroll
            for (int off = 1; off < 32; off <<= 1)
                vmax = fmaxf(vmax, __shfl_xor(vmax, off, 64));
            float vsum = __expf(acc[s][0][r] - vmax) + __expf(acc[s][1][r] - vmax);
#pragma unroll
            for (int off = 1; off < 32; off <<= 1)
                vsum += __shfl_xor(vsum, off, 64);
            if (l31 == 0) {
                int n = n0 + aq + s * 32 + cdrow(r, l5);
                size_t pidx = (size_t)(blockIdx.x * 2 + member2) * NPIX + n;
                prm[pidx] = vmax;
                plr[pidx] = vsum;
            }
        }
}

// out: relu(x + bias + W.Y^T), single batch. grid (32, 4). fp16 single.
__global__ __launch_bounds__(256) void out_mfma(
    const short* __restrict__ wof,
    const float* __restrict__ b_o1, const float* __restrict__ b_o2,
    const short* __restrict__ Y1s, const short* __restrict__ Y2s,
    const float* __restrict__ x, float* __restrict__ out, int b)
{
    const int ch0 = blockIdx.y * 128;
    const int pix0 = blockIdx.x * 128;
    const short* W = wof + (ch0 < 256 ? 0 : 65536) + (size_t)(ch0 & 255) * 256;
    const short* Y = (ch0 < 256 ? Y1s : Y2s) + (size_t)pix0 * 256;
    const float* bias = ch0 < 256 ? b_o1 : b_o2;

    f32x16 acc[2][2] = {};
    mfma_core_f16(W, Y, acc);

    const int t = threadIdx.x, lane = t & 63, w = t >> 6;
    const int l31 = lane & 31, l5 = lane >> 5;
    const int aq = (w & 1) * 64, bq = (w >> 1) * 64;
#pragma unroll
    for (int s = 0; s < 2; s++)
#pragma unroll
        for (int u = 0; u < 2; u++)
#pragma unroll
            for (int r = 0; r < 16; r++) {
                int ch = ch0 + aq + s * 32 + cdrow(r, l5);
                int pix = pix0 + bq + u * 32 + l31;
                int chm = ch & 255;
                float v = acc[s][u][r] + bias[chm] +
                          x[((size_t)b * CC + chm) * NPIX + pix];
                out[((size_t)b * 2 * CC + ch) * NPIX + pix] = fmaxf(v, 0.0f);
            }
}

// combine 64 partials for cols (blocks 0..63) and rows (blocks 64..127).
__global__ __launch_bounds__(256) void stats2_kernel(
    const float* __restrict__ pm, const float* __restrict__ pl,
    const float* __restrict__ prm, const float* __restrict__ plr,
    float* __restrict__ cmv, float* __restrict__ cliv,
    float* __restrict__ rmv, float* __restrict__ rliv)
{
    __shared__ float sm[4][64], sl[4][64];
    const int half = blockIdx.x >> 6;
    const int bx = blockIdx.x & 63;
    const float* Pm = half ? prm : pm;
    const float* Pl = half ? plr : pl;
    float* Om = half ? rmv : cmv;
    float* Ol = half ? rliv : cliv;
    const int t = threadIdx.x;
    const int cl = t & 63, ch = t >> 6;
    const int col = bx * 64 + cl;
    float m = -1e30f, l = 0.0f;
    for (int i = ch * 16; i < ch * 16 + 16; i++) {
        float m2 = Pm[(size_t)i * NPIX + col];
        float l2 = Pl[(size_t)i * NPIX + col];
        float mn = fmaxf(m, m2);
        l = l * __expf(m - mn) + l2 * __expf(m2 - mn);
        m = mn;
    }
    sm[ch][cl] = m;
    sl[ch][cl] = l;
    __syncthreads();
    if (ch == 0) {
#pragma unroll
        for (int j = 1; j < 4; j++) {
            float m2 = sm[j][cl], l2 = sl[j][cl];
            float mn = fmaxf(m, m2);
            l = l * __expf(m - mn) + l2 * __expf(m2 - mn);
            m = mn;
        }
        Om[col] = m;
        Ol[col] = 1.0f / l;
    }
}

// ---------------- pv: on-the-fly P from S, Y-partials = P @ Vt^T ------------
// grid (64 nT, 4 kq, 2 mode) = 512 blocks (2/CU). Block: 64n x 256c over
// K=1024 (its quarter). S read directly (L3-hot); P never materialized.
__global__ __launch_bounds__(256) void pv_kernel(
    const float* __restrict__ S, const short* __restrict__ Vt,
    const float* __restrict__ rmv, const float* __restrict__ rliv,
    const float* __restrict__ cmv, const float* __restrict__ cliv,
    float* __restrict__ Yp)
{
    __shared__ short LA[64 * YST];     //  9216 B
    __shared__ short LB[256 * YST];    // 36864 B
    const int mode = blockIdx.z, kq = blockIdx.y;
    const int n0 = blockIdx.x * 64;
    const int kbase = kq * 1024;

    const int t = threadIdx.x, lane = t & 63, w = t >> 6;
    const int l31 = lane & 31, l5 = lane >> 5;
    const int nst = (w & 1) * 32, cb = (w >> 1) * 128;
    const int ar = t >> 2;            // staging row 0..63
    const int ak = (t & 3) * 16;      // staging k offset (16 m values)

    const float mrow = rmv[n0 + ar];
    const float lrow = rliv[n0 + ar];
    const float* sp = S + (size_t)(n0 + ar) * NPIX + kbase + ak;

    // prologue prefetch (step 0)
    float4 sv0, sv1, sv2, sv3;
    bf16x8 pb[8];
    sv0 = *(const float4*)(sp);
    sv1 = *(const float4*)(sp + 4);
    sv2 = *(const float4*)(sp + 8);
    sv3 = *(const float4*)(sp + 12);
#pragma unroll
    for (int i = 0; i < 4; i++) {
        const short* bp = Vt + (size_t)(i * 64 + ar) * NPIX + kbase + ak;
        pb[2 * i]     = *(const bf16x8*)bp;
        pb[2 * i + 1] = *(const bf16x8*)(bp + 8);
    }

    f32x16 acc[4] = {};
    for (int s = 0; s < 16; s++) {
        // compute fp16 P fragment for this step
        short4v ph0, ph1, ph2, ph3;
        if (mode == 0) {
            ph0.x = f2h(__expf(sv0.x - mrow) * lrow);
            ph0.y = f2h(__expf(sv0.y - mrow) * lrow);
            ph0.z = f2h(__expf(sv0.z - mrow) * lrow);
            ph0.w = f2h(__expf(sv0.w - mrow) * lrow);
            ph1.x = f2h(__expf(sv1.x - mrow) * lrow);
            ph1.y = f2h(__expf(sv1.y - mrow) * lrow);
            ph1.z = f2h(__expf(sv1.z - mrow) * lrow);
            ph1.w = f2h(__expf(sv1.w - mrow) * lrow);
            ph2.x = f2h(__expf(sv2.x - mrow) * lrow);
            ph2.y = f2h(__expf(sv2.y - mrow) * lrow);
            ph2.z = f2h(__expf(sv2.z - mrow) * lrow);
            ph2.w = f2h(__expf(sv2.w - mrow) * lrow);
            ph3.x = f2h(__expf(sv3.x - mrow) * lrow);
            ph3.y = f2h(__expf(sv3.y - mrow) * lrow);
            ph3.z = f2h(__expf(sv3.z - mrow) * lrow);
            ph3.w = f2h(__expf(sv3.w - mrow) * lrow);
        } else {
            const int mg = kbase + s * 64 + ak;
            float4 cm0 = *(const float4*)(cmv + mg);
            float4 cm1 = *(const float4*)(cmv + mg + 4);
            float4 cm2 = *(const float4*)(cmv + mg + 8);
            float4 cm3 = *(const float4*)(cmv + mg + 12);
            float4 cl0 = *(const float4*)(cliv + mg);
            float4 cl1 = *(const float4*)(cliv + mg + 4);
            float4 cl2 = *(const float4*)(cliv + mg + 8);
            float4 cl3 = *(const float4*)(cliv + mg + 12);
            ph0.x = f2h(__expf(sv0.x - cm0.x) * cl0.x);
            ph0.y = f2h(__expf(sv0.y - cm0.y) * cl0.y);
            ph0.z = f2h(__expf(sv0.z - cm0.z) * cl0.z);
            ph0.w = f2h(__expf(sv0.w - cm0.w) * cl0.w);
            ph1.x = f2h(__expf(sv1.x - cm1.x) * cl1.x);
            ph1.y = f2h(__expf(sv1.y - cm1.y) * cl1.y);
            ph1.z = f2h(__expf(sv1.z - cm1.z) * cl1.z);
            ph1.w = f2h(__expf(sv1.w - cm1.w) * cl1.w);
            ph2.x = f2h(__expf(sv2.x - cm2.x) * cl2.x);
            ph2.y = f2h(__expf(sv2.y - cm2.y) * cl2.y);
            ph2.z = f2h(__expf(sv2.z - cm2.z) * cl2.z);
            ph2.w = f2h(__expf(sv2.w - cm2.w) * cl2.w);
            ph3.x = f2h(__expf(sv3.x - cm3.x) * cl3.x);
            ph3.y = f2h(__expf(sv3.y - cm3.y) * cl3.y);
            ph3.z = f2h(__expf(sv3.z - cm3.z) * cl3.z);
            ph3.w = f2h(__expf(sv3.w - cm3.w) * cl3.w);
        }
        __syncthreads();
        *(short4v*)&LA[ar * YST + ak]      = ph0;
        *(short4v*)&LA[ar * YST + ak + 4]  = ph1;
        *(short4v*)&LA[ar * YST + ak + 8]  = ph2;
        *(short4v*)&LA[ar * YST + ak + 12] = ph3;
#pragma unroll
        for (int i = 0; i < 4; i++) {
            *(bf16x8*)&LB[(i * 64 + ar) * YST + ak]     = pb[2 * i];
            *(bf16x8*)&LB[(i * 64 + ar) * YST + ak + 8] = pb[2 * i + 1];
        }
        __syncthreads();
        if (s + 1 < 16) {
            const float* spn = sp + (s + 1) * 64;
            sv0 = *(const float4*)(spn);
            sv1 = *(const float4*)(spn + 4);
            sv2 = *(const float4*)(spn + 8);
            sv3 = *(const float4*)(spn + 12);
            int kg = kbase + (s + 1) * 64 + ak;
#pragma unroll
            for (int i = 0; i < 4; i++) {
                const short* bp = Vt + (size_t)(i * 64 + ar) * NPIX + kg;
                pb[2 * i]     = *(const bf16x8*)bp;
                pb[2 * i + 1] = *(const bf16x8*)(bp + 8);
            }
        }
#pragma unroll
        for (int kc = 0; kc < 4; kc++) {
            f16x8 af = *(const f16x8*)&LA[(nst + l31) * YST + kc * 16 + l5 * 8];
#pragma unroll
            for (int u = 0; u < 4; u++) {
                f16x8 bf = *(const f16x8*)&LB[(cb + u * 32 + l31) * YST + kc * 16 + l5 * 8];
                acc[u] = __builtin_amdgcn_mfma_f32_32x32x16_f16(af, bf, acc[u], 0, 0, 0);
            }
        }
    }

    float* Yo = Yp + (size_t)(mode * 4 + kq) * ((size_t)NPIX * CC);
#pragma unroll
    for (int u = 0; u < 4; u++)
#pragma unroll
        for (int r = 0; r < 16; r++) {
            int rr = cdrow(r, l5);
            Yo[(size_t)(n0 + nst + rr) * CC + cb + u * 32 + l31] = acc[u][r];
        }
}

// sum 4 K-quarter partials -> fp16 Y. grid (1024, 2)
__global__ __launch_bounds__(256) void ycombine_kernel(
    const float* __restrict__ Yp, short* __restrict__ Y1s, short* __restrict__ Y2s)
{
    const int mode = blockIdx.y;
    const size_t CN = (size_t)NPIX * CC;
    size_t idx = (size_t)blockIdx.x * 1024 + threadIdx.x * 4;
    const float* p = Yp + (size_t)mode * 4 * CN + idx;
    float4 v0 = *(const float4*)p;
    float4 v1 = *(const float4*)(p + CN);
    float4 v2 = *(const float4*)(p + 2 * CN);
    float4 v3 = *(const float4*)(p + 3 * CN);
    short4v o;
    o.x = f2h(v0.x + v1.x + v2.x + v3.x);
    o.y = f2h(v0.y + v1.y + v2.y + v3.y);
    o.z = f2h(v0.z + v1.z + v2.z + v3.z);
    o.w = f2h(v0.w + v1.w + v2.w + v3.w);
    *(short4v*)((mode ? Y2s : Y1s) + idx) = o;
}

extern "C" void kernel_launch(void* const* d_in, const int* in_sizes, int n_in,
                              void* d_out, int out_size, void* d_ws, size_t ws_size,
                              hipStream_t stream)
{
    (void)in_sizes; (void)n_in; (void)out_size; (void)ws_size;
    const float* x      = (const float*)d_in[0];
    const float* w_teta = (const float*)d_in[1];
    const float* b_teta = (const float*)d_in[2];
    const float* w_fi   = (const float*)d_in[3];
    const float* b_fi   = (const float*)d_in[4];
    const float* w_gi   = (const float*)d_in[5];
    const float* b_gi   = (const float*)d_in[6];
    const float* w_o1   = (const float*)d_in[7];
    const float* b_o1   = (const float*)d_in[8];
    const float* w_o2   = (const float*)d_in[9];
    const float* b_o2   = (const float*)d_in[10];
    float* out = (float*)d_out;

    const size_t CN = (size_t)CC * NPIX;       // 1M elements
    float* ws    = (float*)d_ws;
    // --- persistent regions ---
    float* S     = ws;                          // 64 MB (4096^2 f32)
    float* Yp    = S + (size_t)NPIX * NPIX;     // 32 MB (2 modes x 4 kq x 4 MB)
    short* x1f   = (short*)(Yp + 8 * CN);       // 8 MB (fp16)
    short* x2tf  = x1f + BB * CN;               // 8 MB (fp16)
    short* Vtb   = x2tf + BB * CN;              // 8 MB (fp16)
    short* Y1s   = Vtb + BB * CN;               // 2 MB
    short* Y2s   = Y1s + CN;                    // 2 MB
    float* cm    = (float*)(Y2s + CN);
    float* cli   = cm + NPIX;
    float* rmv   = cli + NPIX;
    float* rli   = rmv + NPIX;
    float* pm    = rli + NPIX;                  // 64*NPIX = 1 MB
    float* pl    = pm + 64 * NPIX;              // 1 MB
    float* prm   = pl + 64 * NPIX;              // 1 MB
    float* plr   = prm + 64 * NPIX;             // 1 MB
    short* wall  = (short*)(plr + 64 * NPIX);   // 5*65536 fp16 weights
    short* wpf   = wall;                        // teta, fi, gi
    short* wof   = wall + 3 * 65536;            // o1, o2
    // --- aliases (pre-phase only; dead before batch loop writes) ---
    short* xtf  = (short*)S;                    // 8 MB in S
    short* x2f  = (short*)Yp;                   // 8 MB in Yp region
    short* x3f  = x2f + BB * CN;                // 8 MB in Yp region

    dim3 blk(256);
    pack_w5<<<dim3(64, 5), blk, 0, stream>>>(w_teta, w_fi, w_gi, w_o1, w_o2, wall);
    pack_t_f16<<<dim3(128, 8, 4), blk, 0, stream>>>(x, xtf);

    proj_mfma<<<dim3(32, 2, 12), blk, 0, stream>>>(
        wpf, xtf, b_teta, b_fi, b_gi, x1f, x2f, x3f);

    tr16_cn<<<dim3(128, 8, 4), blk, 0, stream>>>(x2f, x2tf);
    packVt_bf<<<dim3(128, 8, 4), blk, 0, stream>>>(x3f, Vtb);

    for (int b = 0; b < BB; b++) {
        scores_mfma<<<dim3(32, 32), blk, 0, stream>>>(
            x1f + b * CN, x2tf + b * CN, S, pm, pl, prm, plr);
        stats2_kernel<<<dim3(128), blk, 0, stream>>>(
            pm, pl, prm, plr, cm, cli, rmv, rli);
        pv_kernel<<<dim3(64, 4, 2), blk, 0, stream>>>(
            S, Vtb + b * CN, rmv, rli, cm, cli, Yp);
        ycombine_kernel<<<dim3(1024, 2), blk, 0, stream>>>(Yp, Y1s, Y2s);
        out_mfma<<<dim3(32, 4), blk, 0, stream>>>(
            wof, b_o1, b_o2, Y1s, Y2s, x, out, b);
    }
}

// Round 4
// 503.862 us; speedup vs baseline: 1.0843x; 1.0843x over previous
//
#include <hip/hip_runtime.h>

#define BB   4
#define CC   256
#define NPIX 4096
#define AST2 40    // mfma-core LDS row stride (shorts), 80 B, 16B-aligned
#define YST  72    // ygemm LDS row stride (shorts), 144 B, 16B-aligned

typedef __attribute__((ext_vector_type(8)))  short bf16x8;
typedef __attribute__((ext_vector_type(8)))  _Float16 f16x8;
typedef __attribute__((ext_vector_type(4)))  short short4v;
typedef __attribute__((ext_vector_type(16))) float f32x16;

__device__ __forceinline__ short f2h(float f) {
    _Float16 h = (_Float16)f;           // v_cvt_f16_f32 (RNE)
    return __builtin_bit_cast(short, h);
}
__device__ __forceinline__ int cdrow(int r, int l5) {
    return (r & 3) + 8 * (r >> 2) + 4 * l5;   // verified m74/m101 C/D row map
}

// ---------------------------------------------------------------------------
// Single-fp16 MFMA core: 128x128 tile, K=256, register-prefetch pipelined.
// 20 KB LDS.
// ---------------------------------------------------------------------------
__device__ __forceinline__ void mfma_core_f16(
    const short* __restrict__ A, const short* __restrict__ B, f32x16 acc[2][2])
{
    __shared__ short LA[128 * AST2], LB[128 * AST2];
    const int t = threadIdx.x;
    const int lane = t & 63, w = t >> 6;
    const int l31 = lane & 31, l5 = lane >> 5;
    const int nq = (w & 1) * 64, mq = (w >> 1) * 64;
    const int sr = t >> 1;
    const int sk = (t & 1) * 16;
    const size_t gs = (size_t)sr * 256 + sk;
    const int ls = sr * AST2 + sk;

    bf16x8 rA0 = *(const bf16x8*)(A + gs);
    bf16x8 rA1 = *(const bf16x8*)(A + gs + 8);
    bf16x8 rB0 = *(const bf16x8*)(B + gs);
    bf16x8 rB1 = *(const bf16x8*)(B + gs + 8);

    for (int k0 = 0; k0 < 256; k0 += 32) {
        __syncthreads();
        *(bf16x8*)&LA[ls]     = rA0;
        *(bf16x8*)&LA[ls + 8] = rA1;
        *(bf16x8*)&LB[ls]     = rB0;
        *(bf16x8*)&LB[ls + 8] = rB1;
        __syncthreads();
        if (k0 + 32 < 256) {
            size_t g = gs + k0 + 32;
            rA0 = *(const bf16x8*)(A + g);
            rA1 = *(const bf16x8*)(A + g + 8);
            rB0 = *(const bf16x8*)(B + g);
            rB1 = *(const bf16x8*)(B + g + 8);
        }
#pragma unroll
        for (int ks = 0; ks < 2; ks++) {
            f16x8 a[2], b[2];
#pragma unroll
            for (int s = 0; s < 2; s++) {
                a[s] = *(const f16x8*)&LA[(nq + s * 32 + l31) * AST2 + ks * 16 + l5 * 8];
                b[s] = *(const f16x8*)&LB[(mq + s * 32 + l31) * AST2 + ks * 16 + l5 * 8];
            }
#pragma unroll
            for (int s = 0; s < 2; s++)
#pragma unroll
                for (int u = 0; u < 2; u++)
                    acc[s][u] = __builtin_amdgcn_mfma_f32_32x32x16_f16(a[s], b[u], acc[s][u], 0, 0, 0);
        }
    }
}

// ---------------- pack kernels ----------------

// all 5 weights fp32 -> fp16, same layout. grid (64, 5)
__global__ __launch_bounds__(256) void pack_w5(
    const float* __restrict__ w0, const float* __restrict__ w1,
    const float* __restrict__ w2, const float* __restrict__ w3,
    const float* __restrict__ w4, short* __restrict__ wall)
{
    int which = blockIdx.y;
    const float* w = which == 0 ? w0 : which == 1 ? w1 : which == 2 ? w2
                   : which == 3 ? w3 : w4;
    int idx = blockIdx.x * 1024 + threadIdx.x * 4;
    float4 v = *(const float4*)(w + idx);
    short4v h;
    h.x = f2h(v.x); h.y = f2h(v.y); h.z = f2h(v.z); h.w = f2h(v.w);
    *(short4v*)(wall + which * 65536 + idx) = h;
}

// transpose fp32 [c][n] -> single fp16 [n][c]. grid (128,8,4)
__global__ __launch_bounds__(256) void pack_t_f16(
    const float* __restrict__ in, short* __restrict__ o16)
{
    __shared__ short T[32][36];
    const int b  = blockIdx.z;
    const int n0 = blockIdx.x * 32;
    const int c0 = blockIdx.y * 32;
    const float* src = in + (size_t)b * CC * NPIX;
    const int t = threadIdx.x;
    const int r = t >> 3, q = t & 7;
    float4 v = *(const float4*)(src + (size_t)(c0 + r) * NPIX + n0 + q * 4);
    T[q * 4 + 0][r] = f2h(v.x);
    T[q * 4 + 1][r] = f2h(v.y);
    T[q * 4 + 2][r] = f2h(v.z);
    T[q * 4 + 3][r] = f2h(v.w);
    __syncthreads();
    short4v o;
    o.x = T[r][q * 4 + 0];
    o.y = T[r][q * 4 + 1];
    o.z = T[r][q * 4 + 2];
    o.w = T[r][q * 4 + 3];
    size_t oo = (size_t)b * CC * NPIX + (size_t)(n0 + r) * 256 + c0 + q * 4;
    *(short4v*)(o16 + oo) = o;
}

// transpose fp16 [256][4096] -> fp16 [4096][256]. grid (128,8,4)
__global__ __launch_bounds__(256) void tr16_cn(
    const short* __restrict__ in, short* __restrict__ outp)
{
    __shared__ short T[32][33];
    const int b  = blockIdx.z;
    const int n0 = blockIdx.x * 32;
    const int c0 = blockIdx.y * 32;
    const short* src = in + (size_t)b * CC * NPIX;
    short* dst = outp + (size_t)b * CC * NPIX;
    const int t = threadIdx.x;
    const int r = t >> 3, q = t & 7;
    short4v v = *(const short4v*)(src + (size_t)(c0 + r) * NPIX + n0 + q * 4);
    T[q * 4 + 0][r] = v.x;
    T[q * 4 + 1][r] = v.y;
    T[q * 4 + 2][r] = v.z;
    T[q * 4 + 3][r] = v.w;
    __syncthreads();
    short4v o;
    o.x = T[r][q * 4 + 0];
    o.y = T[r][q * 4 + 1];
    o.z = T[r][q * 4 + 2];
    o.w = T[r][q * 4 + 3];
    *(short4v*)(dst + (size_t)(n0 + r) * 256 + c0 + q * 4) = o;
}

// Vt[c][m] = x3f.flat[m*256+c] (already fp16). grid (128,8,4)
__global__ __launch_bounds__(256) void packVt_bf(
    const short* __restrict__ x3f, short* __restrict__ Vt)
{
    __shared__ short T[32][33];
    const int b  = blockIdx.z;
    const int m0 = blockIdx.x * 32;
    const int c0 = blockIdx.y * 32;
    const short* in = x3f + (size_t)b * CC * NPIX;
    short* out = Vt + (size_t)b * CC * NPIX;
    const int t = threadIdx.x;
    const int r = t >> 3, q = t & 7;
    short4v v = *(const short4v*)(in + (size_t)(m0 + r) * CC + c0 + q * 4);
    T[q * 4 + 0][r] = v.x;
    T[q * 4 + 1][r] = v.y;
    T[q * 4 + 2][r] = v.z;
    T[q * 4 + 3][r] = v.w;
    __syncthreads();
    short4v o;
    o.x = T[r][q * 4 + 0];
    o.y = T[r][q * 4 + 1];
    o.z = T[r][q * 4 + 2];
    o.w = T[r][q * 4 + 3];
    *(short4v*)(out + (size_t)(c0 + r) * NPIX + m0 + q * 4) = o;
}

// ---------------- GEMM kernels ----------------

// proj. grid (32, 2, 12). p=0 -> x1, p=1 -> x2, p=2 -> x3; all fp16 [c][n].
__global__ __launch_bounds__(256) void proj_mfma(
    const short* __restrict__ wpf, const short* __restrict__ xtf,
    const float* __restrict__ b_teta, const float* __restrict__ b_fi,
    const float* __restrict__ b_gi,
    short* __restrict__ x1f, short* __restrict__ x2f, short* __restrict__ x3f)
{
    const int z = blockIdx.z, p = z >> 2, b = z & 3;
    const int n0 = blockIdx.x * 128, c0 = blockIdx.y * 128;
    const size_t CN = (size_t)CC * NPIX;
    const short* Ah = wpf + p * 65536 + c0 * 256;
    const short* Bh = xtf + (size_t)b * CN + (size_t)n0 * 256;
    const float* bias = p == 0 ? b_teta : p == 1 ? b_fi : b_gi;
    short* dst = p == 0 ? x1f : p == 1 ? x2f : x3f;

    f32x16 acc[2][2] = {};
    mfma_core_f16(Ah, Bh, acc);

    const int t = threadIdx.x, lane = t & 63, w = t >> 6;
    const int l31 = lane & 31, l5 = lane >> 5;
    const int aq = (w & 1) * 64, bq = (w >> 1) * 64;
#pragma unroll
    for (int s = 0; s < 2; s++)
#pragma unroll
        for (int u = 0; u < 2; u++)
#pragma unroll
            for (int r = 0; r < 16; r++) {
                int c = c0 + aq + s * 32 + cdrow(r, l5);
                int n = n0 + bq + u * 32 + l31;
                float v = acc[s][u][r] + bias[c];
                size_t o = (size_t)b * CN + (size_t)c * NPIX + n;
                dst[o] = f2h(v);
            }
}

// scores + fused column partial stats. grid (32, 32) per batch. fp16 single.
__global__ __launch_bounds__(256) void scores_mfma(
    const short* __restrict__ x1f, const short* __restrict__ x2tf,
    float* __restrict__ S, float* __restrict__ pm, float* __restrict__ pl)
{
    const int m0 = blockIdx.x * 128, n0 = blockIdx.y * 128;
    f32x16 acc[2][2] = {};
    mfma_core_f16(x1f + (size_t)n0 * 256, x2tf + (size_t)m0 * 256, acc);

    const int t = threadIdx.x, lane = t & 63, w = t >> 6;
    const int l31 = lane & 31, l5 = lane >> 5;
    const int aq = (w & 1) * 64, bq = (w >> 1) * 64;
#pragma unroll
    for (int s = 0; s < 2; s++)
#pragma unroll
        for (int u = 0; u < 2; u++)
#pragma unroll
            for (int r = 0; r < 16; r++) {
                int n = n0 + aq + s * 32 + cdrow(r, l5);
                int m = m0 + bq + u * 32 + l31;
                S[(size_t)n * NPIX + m] = acc[s][u][r];
            }

    // column partial stats over this block's 64-row half (member = w&1).
    const int member = w & 1;
#pragma unroll
    for (int u = 0; u < 2; u++) {
        float vmax = -1e30f;
#pragma unroll
        for (int s = 0; s < 2; s++)
#pragma unroll
            for (int r = 0; r < 16; r++) vmax = fmaxf(vmax, acc[s][u][r]);
        float vsum = 0.0f;
#pragma unroll
        for (int s = 0; s < 2; s++)
#pragma unroll
            for (int r = 0; r < 16; r++) vsum += __expf(acc[s][u][r] - vmax);
        // combine with partner lane (lane^32) holding the other 16 rows/stripe
        float vmax2 = __shfl_xor(vmax, 32, 64);
        float vsum2 = __shfl_xor(vsum, 32, 64);
        float mc = fmaxf(vmax, vmax2);
        float sc = vsum * __expf(vmax - mc) + vsum2 * __expf(vmax2 - mc);
        if (l5 == 0) {
            size_t pidx = (size_t)(blockIdx.y * 2 + member) * NPIX + m0 + bq + u * 32 + l31;
            pm[pidx] = mc;
            pl[pidx] = sc;
        }
    }
}

// out: relu(x + bias + W.(sum_q Ypq)^T), single batch. grid (32, 4).
// B operand = sum of 4 fp16 K-quarter partials, combined during staging.
__global__ __launch_bounds__(256) void out_mfma(
    const short* __restrict__ wof,
    const float* __restrict__ b_o1, const float* __restrict__ b_o2,
    const short* __restrict__ Yp,
    const float* __restrict__ x, float* __restrict__ out, int b)
{
    __shared__ short LA[128 * AST2], LB[128 * AST2];
    const size_t CN_ = (size_t)NPIX * CC;
    const int ch0 = blockIdx.y * 128;
    const int pix0 = blockIdx.x * 128;
    const int mode = ch0 < 256 ? 0 : 1;
    const short* W = wof + mode * 65536 + (size_t)(ch0 & 255) * 256;
    const short* Yq = Yp + (size_t)mode * 4 * CN_;
    const float* bias = mode == 0 ? b_o1 : b_o2;

    const int t = threadIdx.x, lane = t & 63, w = t >> 6;
    const int l31 = lane & 31, l5 = lane >> 5;
    const int nq = (w & 1) * 64, mq = (w >> 1) * 64;
    const int sr = t >> 1;
    const int sk = (t & 1) * 16;
    const size_t gsA = (size_t)sr * 256 + sk;
    const size_t gsB = (size_t)(pix0 + sr) * 256 + sk;
    const int ls = sr * AST2 + sk;

    f32x16 acc[2][2] = {};

    bf16x8 rA0 = *(const bf16x8*)(W + gsA);
    bf16x8 rA1 = *(const bf16x8*)(W + gsA + 8);
    f16x8 rB0, rB1;
    {
        f16x8 a0 = *(const f16x8*)(Yq + gsB);
        f16x8 a1 = *(const f16x8*)(Yq + CN_ + gsB);
        f16x8 a2 = *(const f16x8*)(Yq + 2 * CN_ + gsB);
        f16x8 a3 = *(const f16x8*)(Yq + 3 * CN_ + gsB);
        rB0 = (a0 + a1) + (a2 + a3);
        f16x8 c0 = *(const f16x8*)(Yq + gsB + 8);
        f16x8 c1 = *(const f16x8*)(Yq + CN_ + gsB + 8);
        f16x8 c2 = *(const f16x8*)(Yq + 2 * CN_ + gsB + 8);
        f16x8 c3 = *(const f16x8*)(Yq + 3 * CN_ + gsB + 8);
        rB1 = (c0 + c1) + (c2 + c3);
    }

    for (int k0 = 0; k0 < 256; k0 += 32) {
        __syncthreads();
        *(bf16x8*)&LA[ls]    = rA0;
        *(bf16x8*)&LA[ls + 8] = rA1;
        *(f16x8*)&LB[ls]     = rB0;
        *(f16x8*)&LB[ls + 8] = rB1;
        __syncthreads();
        if (k0 + 32 < 256) {
            size_t gA = gsA + k0 + 32;
            size_t gB = gsB + k0 + 32;
            rA0 = *(const bf16x8*)(W + gA);
            rA1 = *(const bf16x8*)(W + gA + 8);
            f16x8 a0 = *(const f16x8*)(Yq + gB);
            f16x8 a1 = *(const f16x8*)(Yq + CN_ + gB);
            f16x8 a2 = *(const f16x8*)(Yq + 2 * CN_ + gB);
            f16x8 a3 = *(const f16x8*)(Yq + 3 * CN_ + gB);
            rB0 = (a0 + a1) + (a2 + a3);
            f16x8 c0 = *(const f16x8*)(Yq + gB + 8);
            f16x8 c1 = *(const f16x8*)(Yq + CN_ + gB + 8);
            f16x8 c2 = *(const f16x8*)(Yq + 2 * CN_ + gB + 8);
            f16x8 c3 = *(const f16x8*)(Yq + 3 * CN_ + gB + 8);
            rB1 = (c0 + c1) + (c2 + c3);
        }
#pragma unroll
        for (int ks = 0; ks < 2; ks++) {
            f16x8 a[2], bb[2];
#pragma unroll
            for (int s = 0; s < 2; s++) {
                a[s]  = *(const f16x8*)&LA[(nq + s * 32 + l31) * AST2 + ks * 16 + l5 * 8];
                bb[s] = *(const f16x8*)&LB[(mq + s * 32 + l31) * AST2 + ks * 16 + l5 * 8];
            }
#pragma unroll
            for (int s = 0; s < 2; s++)
#pragma unroll
                for (int u = 0; u < 2; u++)
                    acc[s][u] = __builtin_amdgcn_mfma_f32_32x32x16_f16(a[s], bb[u], acc[s][u], 0, 0, 0);
        }
    }

    const int aq = (w & 1) * 64, bq = (w >> 1) * 64;
#pragma unroll
    for (int s = 0; s < 2; s++)
#pragma unroll
        for (int u = 0; u < 2; u++)
#pragma unroll
            for (int r = 0; r < 16; r++) {
                int ch = ch0 + aq + s * 32 + cdrow(r, l5);
                int pix = pix0 + bq + u * 32 + l31;
                int chm = ch & 255;
                float v = acc[s][u][r] + bias[chm] +
                          x[((size_t)b * CC + chm) * NPIX + pix];
                out[((size_t)b * 2 * CC + ch) * NPIX + pix] = fmaxf(v, 0.0f);
            }
}

// combine 64 col partials. grid (64); 4 chunk-threads per column.
__global__ __launch_bounds__(256) void colstats2_kernel(
    const float* __restrict__ pm, const float* __restrict__ pl,
    float* __restrict__ cm, float* __restrict__ cli)
{
    __shared__ float sm[4][64], sl[4][64];
    const int t = threadIdx.x;
    const int cl = t & 63, ch = t >> 6;
    const int col = blockIdx.x * 64 + cl;
    float m = -1e30f, l = 0.0f;
    for (int i = ch * 16; i < ch * 16 + 16; i++) {
        float m2 = pm[(size_t)i * NPIX + col];
        float l2 = pl[(size_t)i * NPIX + col];
        float mn = fmaxf(m, m2);
        l = l * __expf(m - mn) + l2 * __expf(m2 - mn);
        m = mn;
    }
    sm[ch][cl] = m;
    sl[ch][cl] = l;
    __syncthreads();
    if (ch == 0) {
#pragma unroll
        for (int j = 1; j < 4; j++) {
            float m2 = sm[j][cl], l2 = sl[j][cl];
            float mn = fmaxf(m, m2);
            l = l * __expf(m - mn) + l2 * __expf(m2 - mn);
            m = mn;
        }
        cm[col]  = m;
        cli[col] = 1.0f / l;
    }
}

// ---------------- fused row-stats + P materialization (fp16 P) --------------
__global__ __launch_bounds__(256) void rowexpP_kernel(
    const float* __restrict__ S, int n_off,
    const float* __restrict__ colm, const float* __restrict__ colli,
    short* __restrict__ P1, short* __restrict__ P2)
{
    const int row = blockIdx.x;
    const int n = n_off + row;
    const float* sp = S + (size_t)n * NPIX;
    const int t = threadIdx.x;
    const int w = t >> 6, lane = t & 63;
    __shared__ float red[4];

    float4 s4[4];
#pragma unroll
    for (int i = 0; i < 4; i++)
        s4[i] = *(const float4*)(sp + (i * 256 + t) * 4);

    float m = -1e30f;
#pragma unroll
    for (int i = 0; i < 4; i++) {
        m = fmaxf(m, fmaxf(fmaxf(s4[i].x, s4[i].y), fmaxf(s4[i].z, s4[i].w)));
    }
    for (int off = 32; off; off >>= 1) m = fmaxf(m, __shfl_xor(m, off, 64));
    if (lane == 0) red[w] = m;
    __syncthreads();
    m = fmaxf(fmaxf(red[0], red[1]), fmaxf(red[2], red[3]));
    __syncthreads();

    float e[16];
    float sum = 0.0f;
#pragma unroll
    for (int i = 0; i < 4; i++) {
        e[i * 4 + 0] = __expf(s4[i].x - m);
        e[i * 4 + 1] = __expf(s4[i].y - m);
        e[i * 4 + 2] = __expf(s4[i].z - m);
        e[i * 4 + 3] = __expf(s4[i].w - m);
        sum += e[i * 4 + 0] + e[i * 4 + 1] + e[i * 4 + 2] + e[i * 4 + 3];
    }
    for (int off = 32; off; off >>= 1) sum += __shfl_xor(sum, off, 64);
    if (lane == 0) red[w] = sum;
    __syncthreads();
    float rl = 1.0f / (red[0] + red[1] + red[2] + red[3]);

    short* p1 = P1 + (size_t)row * NPIX;
    short* p2 = P2 + (size_t)row * NPIX;
#pragma unroll
    for (int i = 0; i < 4; i++) {
        int idx = (i * 256 + t) * 4;
        float4 cm4 = *(const float4*)(colm + idx);
        float4 cl4 = *(const float4*)(colli + idx);
        short4v a, bvv;
        a.x = f2h(e[i * 4 + 0] * rl);
        a.y = f2h(e[i * 4 + 1] * rl);
        a.z = f2h(e[i * 4 + 2] * rl);
        a.w = f2h(e[i * 4 + 3] * rl);
        bvv.x = f2h(__expf(s4[i].x - cm4.x) * cl4.x);
        bvv.y = f2h(__expf(s4[i].y - cm4.y) * cl4.y);
        bvv.z = f2h(__expf(s4[i].z - cm4.z) * cl4.z);
        bvv.w = f2h(__expf(s4[i].w - cm4.w) * cl4.w);
        *(short4v*)(p1 + idx) = a;
        *(short4v*)(p2 + idx) = bvv;
    }
}

// ---------------- Y = P @ Vt^T: K-split fp16 partials ----------------
// grid (64 nT, 4 kq, 2 mode) = 512 blocks (2/CU). Block: 64n x 256c over
// K=1024 (its quarter). P segment read exactly once; Vt L2-hot.
__global__ __launch_bounds__(256) void ygemm_kernel(
    const short* __restrict__ P1a, const short* __restrict__ P1b,
    const short* __restrict__ P2a, const short* __restrict__ P2b,
    const short* __restrict__ Vt, short* __restrict__ Yp)
{
    __shared__ short LA[64 * YST];     //  9216 B
    __shared__ short LB[256 * YST];    // 36864 B
    const int mode = blockIdx.z, kq = blockIdx.y;
    const int n0 = blockIdx.x * 64;
    const short* Pa_ = mode ? P2a : P1a;
    const short* Pb_ = mode ? P2b : P1b;
    const short* A = (n0 < 2048) ? (Pa_ + (size_t)n0 * NPIX)
                                 : (Pb_ + (size_t)(n0 - 2048) * NPIX);
    const short* B = Vt;
    const int kbase = kq * 1024;

    const int t = threadIdx.x, lane = t & 63, w = t >> 6;
    const int l31 = lane & 31, l5 = lane >> 5;
    const int nst = (w & 1) * 32, cb = (w >> 1) * 128;
    const int ar = t >> 2;            // staging row 0..63
    const int ak = (t & 3) * 16;      // staging k offset (shorts)

    // prologue prefetch (step 0)
    bf16x8 pa[2], pb[8];
    {
        const short* ap = A + (size_t)ar * NPIX + kbase + ak;
        pa[0] = *(const bf16x8*)ap;
        pa[1] = *(const bf16x8*)(ap + 8);
#pragma unroll
        for (int i = 0; i < 4; i++) {
            const short* bp = B + (size_t)(i * 64 + ar) * NPIX + kbase + ak;
            pb[2 * i]     = *(const bf16x8*)bp;
            pb[2 * i + 1] = *(const bf16x8*)(bp + 8);
        }
    }

    f32x16 acc[4] = {};
    for (int s = 0; s < 16; s++) {
        __syncthreads();
        *(bf16x8*)&LA[ar * YST + ak]     = pa[0];
        *(bf16x8*)&LA[ar * YST + ak + 8] = pa[1];
#pragma unroll
        for (int i = 0; i < 4; i++) {
            *(bf16x8*)&LB[(i * 64 + ar) * YST + ak]     = pb[2 * i];
            *(bf16x8*)&LB[(i * 64 + ar) * YST + ak + 8] = pb[2 * i + 1];
        }
        __syncthreads();
        if (s + 1 < 16) {
            int kg = kbase + (s + 1) * 64 + ak;
            const short* ap = A + (size_t)ar * NPIX + kg;
            pa[0] = *(const bf16x8*)ap;
            pa[1] = *(const bf16x8*)(ap + 8);
#pragma unroll
            for (int i = 0; i < 4; i++) {
                const short* bp = B + (size_t)(i * 64 + ar) * NPIX + kg;
                pb[2 * i]     = *(const bf16x8*)bp;
                pb[2 * i + 1] = *(const bf16x8*)(bp + 8);
            }
        }
#pragma unroll
        for (int kc = 0; kc < 4; kc++) {
            f16x8 af = *(const f16x8*)&LA[(nst + l31) * YST + kc * 16 + l5 * 8];
#pragma unroll
            for (int u = 0; u < 4; u++) {
                f16x8 bf = *(const f16x8*)&LB[(cb + u * 32 + l31) * YST + kc * 16 + l5 * 8];
                acc[u] = __builtin_amdgcn_mfma_f32_32x32x16_f16(af, bf, acc[u], 0, 0, 0);
            }
        }
    }

    short* Yo = Yp + (size_t)(mode * 4 + kq) * ((size_t)NPIX * CC);
#pragma unroll
    for (int u = 0; u < 4; u++)
#pragma unroll
        for (int r = 0; r < 16; r++) {
            int rr = cdrow(r, l5);
            Yo[(size_t)(n0 + nst + rr) * CC + cb + u * 32 + l31] = f2h(acc[u][r]);
        }
}

extern "C" void kernel_launch(void* const* d_in, const int* in_sizes, int n_in,
                              void* d_out, int out_size, void* d_ws, size_t ws_size,
                              hipStream_t stream)
{
    (void)in_sizes; (void)n_in; (void)out_size; (void)ws_size;
    const float* x      = (const float*)d_in[0];
    const float* w_teta = (const float*)d_in[1];
    const float* b_teta = (const float*)d_in[2];
    const float* w_fi   = (const float*)d_in[3];
    const float* b_fi   = (const float*)d_in[4];
    const float* w_gi   = (const float*)d_in[5];
    const float* b_gi   = (const float*)d_in[6];
    const float* w_o1   = (const float*)d_in[7];
    const float* b_o1   = (const float*)d_in[8];
    const float* w_o2   = (const float*)d_in[9];
    const float* b_o2   = (const float*)d_in[10];
    float* out = (float*)d_out;

    const size_t CN = (size_t)CC * NPIX;       // 1M elements
    const size_t HALF = (size_t)2048 * NPIX;   // 8M shorts = 16 MB
    float* ws    = (float*)d_ws;
    // --- persistent regions ---
    float* S     = ws;                          // 64 MB
    short* Pfr   = (short*)(S + (size_t)NPIX * NPIX);  // 32 MB (P1a+P2a)
    short* x1f   = Pfr + 2 * HALF;              // 8 MB (fp16)
    short* x2tf  = x1f + BB * CN;               // 8 MB (fp16)
    short* Vtb   = x2tf + BB * CN;              // 8 MB (fp16)
    float* cm    = (float*)(Vtb + BB * CN);
    float* cli   = cm + NPIX;
    float* pm    = cli + NPIX;                  // 64*NPIX = 1 MB
    float* pl    = pm + 64 * NPIX;              // 1 MB
    short* wall  = (short*)(pl + 64 * NPIX);    // 5*65536 fp16 weights
    short* wpf   = wall;                        // teta, fi, gi
    short* wof   = wall + 3 * 65536;            // o1, o2
    // --- aliases (pre-phase only) ---
    short* xtf  = (short*)S;                    // 8 MB in S
    short* x2f  = (short*)Pfr;                  // 8 MB
    short* x3f  = x2f + BB * CN;                // 8 MB
    // P halves: a-halves in Pfr, b-halves overwrite S's first 32 MB
    short* P1a = Pfr;
    short* P2a = Pfr + HALF;
    short* P1b = (short*)S;
    short* P2b = (short*)S + HALF;
    // Yp fp16 partials (8 x 2 MB) alias S's upper 32 MB — dead after rowexpP;
    // consumed by out_mfma before next scores_mfma rewrites S.
    short* Yp  = (short*)(S + (size_t)8 * 1024 * 1024);

    dim3 blk(256);
    pack_w5<<<dim3(64, 5), blk, 0, stream>>>(w_teta, w_fi, w_gi, w_o1, w_o2, wall);
    pack_t_f16<<<dim3(128, 8, 4), blk, 0, stream>>>(x, xtf);

    proj_mfma<<<dim3(32, 2, 12), blk, 0, stream>>>(
        wpf, xtf, b_teta, b_fi, b_gi, x1f, x2f, x3f);

    tr16_cn<<<dim3(128, 8, 4), blk, 0, stream>>>(x2f, x2tf);
    packVt_bf<<<dim3(128, 8, 4), blk, 0, stream>>>(x3f, Vtb);

    for (int b = 0; b < BB; b++) {
        scores_mfma<<<dim3(32, 32), blk, 0, stream>>>(
            x1f + b * CN, x2tf + b * CN, S, pm, pl);
        colstats2_kernel<<<dim3(64), blk, 0, stream>>>(pm, pl, cm, cli);
        // half 1: rows [0,2048) -> Pfr ; half 2: rows [2048,4096) -> S base
        rowexpP_kernel<<<dim3(2048), blk, 0, stream>>>(S, 0, cm, cli, P1a, P2a);
        rowexpP_kernel<<<dim3(2048), blk, 0, stream>>>(S, 2048, cm, cli, P1b, P2b);
        ygemm_kernel<<<dim3(64, 4, 2), blk, 0, stream>>>(
            P1a, P1b, P2a, P2b, Vtb + b * CN, Yp);
        out_mfma<<<dim3(32, 4), blk, 0, stream>>>(
            wof, b_o1, b_o2, Yp, x, out, b);
    }
}

// Round 5
// 473.318 us; speedup vs baseline: 1.1542x; 1.0645x over previous
//
#include <hip/hip_runtime.h>

#define BB   4
#define CC   256
#define NPIX 4096
#define AST2 40    // mfma-core LDS row stride (shorts), 80 B, 16B-aligned
#define YST  72    // ygemm LDS row stride (shorts), 144 B, 16B-aligned

typedef __attribute__((ext_vector_type(8)))  short bf16x8;
typedef __attribute__((ext_vector_type(8)))  _Float16 f16x8;
typedef __attribute__((ext_vector_type(4)))  short short4v;
typedef __attribute__((ext_vector_type(16))) float f32x16;

__device__ __forceinline__ short f2h(float f) {
    _Float16 h = (_Float16)f;           // v_cvt_f16_f32 (RNE)
    return __builtin_bit_cast(short, h);
}
__device__ __forceinline__ int cdrow(int r, int l5) {
    return (r & 3) + 8 * (r >> 2) + 4 * l5;   // verified m74/m101 C/D row map
}
// S fixed-point codec: s in (-128,128), scale 256 -> |err| <= 2^-9
__device__ __forceinline__ short s_enc(float v) {
    float c = fmaxf(fminf(v, 127.9f), -127.9f);
    return (short)__float2int_rn(c * 256.0f);
}
__device__ __forceinline__ float s_dec(short v) {
    return (float)v * (1.0f / 256.0f);
}

// ---------------------------------------------------------------------------
// Single-fp16 MFMA core: 128x128 tile, K=256, register-prefetch pipelined.
// 20 KB LDS.
// ---------------------------------------------------------------------------
__device__ __forceinline__ void mfma_core_f16(
    const short* __restrict__ A, const short* __restrict__ B, f32x16 acc[2][2])
{
    __shared__ short LA[128 * AST2], LB[128 * AST2];
    const int t = threadIdx.x;
    const int lane = t & 63, w = t >> 6;
    const int l31 = lane & 31, l5 = lane >> 5;
    const int nq = (w & 1) * 64, mq = (w >> 1) * 64;
    const int sr = t >> 1;
    const int sk = (t & 1) * 16;
    const size_t gs = (size_t)sr * 256 + sk;
    const int ls = sr * AST2 + sk;

    bf16x8 rA0 = *(const bf16x8*)(A + gs);
    bf16x8 rA1 = *(const bf16x8*)(A + gs + 8);
    bf16x8 rB0 = *(const bf16x8*)(B + gs);
    bf16x8 rB1 = *(const bf16x8*)(B + gs + 8);

    for (int k0 = 0; k0 < 256; k0 += 32) {
        __syncthreads();
        *(bf16x8*)&LA[ls]     = rA0;
        *(bf16x8*)&LA[ls + 8] = rA1;
        *(bf16x8*)&LB[ls]     = rB0;
        *(bf16x8*)&LB[ls + 8] = rB1;
        __syncthreads();
        if (k0 + 32 < 256) {
            size_t g = gs + k0 + 32;
            rA0 = *(const bf16x8*)(A + g);
            rA1 = *(const bf16x8*)(A + g + 8);
            rB0 = *(const bf16x8*)(B + g);
            rB1 = *(const bf16x8*)(B + g + 8);
        }
#pragma unroll
        for (int ks = 0; ks < 2; ks++) {
            f16x8 a[2], b[2];
#pragma unroll
            for (int s = 0; s < 2; s++) {
                a[s] = *(const f16x8*)&LA[(nq + s * 32 + l31) * AST2 + ks * 16 + l5 * 8];
                b[s] = *(const f16x8*)&LB[(mq + s * 32 + l31) * AST2 + ks * 16 + l5 * 8];
            }
#pragma unroll
            for (int s = 0; s < 2; s++)
#pragma unroll
                for (int u = 0; u < 2; u++)
                    acc[s][u] = __builtin_amdgcn_mfma_f32_32x32x16_f16(a[s], b[u], acc[s][u], 0, 0, 0);
        }
    }
}

// ---------------- pack kernels ----------------

// all 5 weights fp32 -> fp16, same layout. grid (64, 5)
__global__ __launch_bounds__(256) void pack_w5(
    const float* __restrict__ w0, const float* __restrict__ w1,
    const float* __restrict__ w2, const float* __restrict__ w3,
    const float* __restrict__ w4, short* __restrict__ wall)
{
    int which = blockIdx.y;
    const float* w = which == 0 ? w0 : which == 1 ? w1 : which == 2 ? w2
                   : which == 3 ? w3 : w4;
    int idx = blockIdx.x * 1024 + threadIdx.x * 4;
    float4 v = *(const float4*)(w + idx);
    short4v h;
    h.x = f2h(v.x); h.y = f2h(v.y); h.z = f2h(v.z); h.w = f2h(v.w);
    *(short4v*)(wall + which * 65536 + idx) = h;
}

// transpose fp32 [c][n] -> single fp16 [n][c]. grid (128,8,4)
__global__ __launch_bounds__(256) void pack_t_f16(
    const float* __restrict__ in, short* __restrict__ o16)
{
    __shared__ short T[32][36];
    const int b  = blockIdx.z;
    const int n0 = blockIdx.x * 32;
    const int c0 = blockIdx.y * 32;
    const float* src = in + (size_t)b * CC * NPIX;
    const int t = threadIdx.x;
    const int r = t >> 3, q = t & 7;
    float4 v = *(const float4*)(src + (size_t)(c0 + r) * NPIX + n0 + q * 4);
    T[q * 4 + 0][r] = f2h(v.x);
    T[q * 4 + 1][r] = f2h(v.y);
    T[q * 4 + 2][r] = f2h(v.z);
    T[q * 4 + 3][r] = f2h(v.w);
    __syncthreads();
    short4v o;
    o.x = T[r][q * 4 + 0];
    o.y = T[r][q * 4 + 1];
    o.z = T[r][q * 4 + 2];
    o.w = T[r][q * 4 + 3];
    size_t oo = (size_t)b * CC * NPIX + (size_t)(n0 + r) * 256 + c0 + q * 4;
    *(short4v*)(o16 + oo) = o;
}

// transpose fp16 [256][4096] -> fp16 [4096][256]. grid (128,8,4)
__global__ __launch_bounds__(256) void tr16_cn(
    const short* __restrict__ in, short* __restrict__ outp)
{
    __shared__ short T[32][33];
    const int b  = blockIdx.z;
    const int n0 = blockIdx.x * 32;
    const int c0 = blockIdx.y * 32;
    const short* src = in + (size_t)b * CC * NPIX;
    short* dst = outp + (size_t)b * CC * NPIX;
    const int t = threadIdx.x;
    const int r = t >> 3, q = t & 7;
    short4v v = *(const short4v*)(src + (size_t)(c0 + r) * NPIX + n0 + q * 4);
    T[q * 4 + 0][r] = v.x;
    T[q * 4 + 1][r] = v.y;
    T[q * 4 + 2][r] = v.z;
    T[q * 4 + 3][r] = v.w;
    __syncthreads();
    short4v o;
    o.x = T[r][q * 4 + 0];
    o.y = T[r][q * 4 + 1];
    o.z = T[r][q * 4 + 2];
    o.w = T[r][q * 4 + 3];
    *(short4v*)(dst + (size_t)(n0 + r) * 256 + c0 + q * 4) = o;
}

// Vt[c][m] = x3f.flat[m*256+c] (already fp16). grid (128,8,4)
__global__ __launch_bounds__(256) void packVt_bf(
    const short* __restrict__ x3f, short* __restrict__ Vt)
{
    __shared__ short T[32][33];
    const int b  = blockIdx.z;
    const int m0 = blockIdx.x * 32;
    const int c0 = blockIdx.y * 32;
    const short* in = x3f + (size_t)b * CC * NPIX;
    short* out = Vt + (size_t)b * CC * NPIX;
    const int t = threadIdx.x;
    const int r = t >> 3, q = t & 7;
    short4v v = *(const short4v*)(in + (size_t)(m0 + r) * CC + c0 + q * 4);
    T[q * 4 + 0][r] = v.x;
    T[q * 4 + 1][r] = v.y;
    T[q * 4 + 2][r] = v.z;
    T[q * 4 + 3][r] = v.w;
    __syncthreads();
    short4v o;
    o.x = T[r][q * 4 + 0];
    o.y = T[r][q * 4 + 1];
    o.z = T[r][q * 4 + 2];
    o.w = T[r][q * 4 + 3];
    *(short4v*)(out + (size_t)(c0 + r) * NPIX + m0 + q * 4) = o;
}

// ---------------- GEMM kernels ----------------

// proj. grid (32, 2, 12). p=0 -> x1, p=1 -> x2, p=2 -> x3; all fp16 [c][n].
__global__ __launch_bounds__(256) void proj_mfma(
    const short* __restrict__ wpf, const short* __restrict__ xtf,
    const float* __restrict__ b_teta, const float* __restrict__ b_fi,
    const float* __restrict__ b_gi,
    short* __restrict__ x1f, short* __restrict__ x2f, short* __restrict__ x3f)
{
    const int z = blockIdx.z, p = z >> 2, b = z & 3;
    const int n0 = blockIdx.x * 128, c0 = blockIdx.y * 128;
    const size_t CN = (size_t)CC * NPIX;
    const short* Ah = wpf + p * 65536 + c0 * 256;
    const short* Bh = xtf + (size_t)b * CN + (size_t)n0 * 256;
    const float* bias = p == 0 ? b_teta : p == 1 ? b_fi : b_gi;
    short* dst = p == 0 ? x1f : p == 1 ? x2f : x3f;

    f32x16 acc[2][2] = {};
    mfma_core_f16(Ah, Bh, acc);

    const int t = threadIdx.x, lane = t & 63, w = t >> 6;
    const int l31 = lane & 31, l5 = lane >> 5;
    const int aq = (w & 1) * 64, bq = (w >> 1) * 64;
#pragma unroll
    for (int s = 0; s < 2; s++)
#pragma unroll
        for (int u = 0; u < 2; u++)
#pragma unroll
            for (int r = 0; r < 16; r++) {
                int c = c0 + aq + s * 32 + cdrow(r, l5);
                int n = n0 + bq + u * 32 + l31;
                float v = acc[s][u][r] + bias[c];
                size_t o = (size_t)b * CN + (size_t)c * NPIX + n;
                dst[o] = f2h(v);
            }
}

// scores + fused column partial stats. S stored int16 fixed-point (x256).
// grid (32, 32) per batch.
__global__ __launch_bounds__(256) void scores_mfma(
    const short* __restrict__ x1f, const short* __restrict__ x2tf,
    short* __restrict__ S16, float* __restrict__ pm, float* __restrict__ pl)
{
    const int m0 = blockIdx.x * 128, n0 = blockIdx.y * 128;
    f32x16 acc[2][2] = {};
    mfma_core_f16(x1f + (size_t)n0 * 256, x2tf + (size_t)m0 * 256, acc);

    const int t = threadIdx.x, lane = t & 63, w = t >> 6;
    const int l31 = lane & 31, l5 = lane >> 5;
    const int aq = (w & 1) * 64, bq = (w >> 1) * 64;
#pragma unroll
    for (int s = 0; s < 2; s++)
#pragma unroll
        for (int u = 0; u < 2; u++)
#pragma unroll
            for (int r = 0; r < 16; r++) {
                int n = n0 + aq + s * 32 + cdrow(r, l5);
                int m = m0 + bq + u * 32 + l31;
                S16[(size_t)n * NPIX + m] = s_enc(acc[s][u][r]);
            }

    // column partial stats over this block's 64-row half (member = w&1).
    const int member = w & 1;
#pragma unroll
    for (int u = 0; u < 2; u++) {
        float vmax = -1e30f;
#pragma unroll
        for (int s = 0; s < 2; s++)
#pragma unroll
            for (int r = 0; r < 16; r++) vmax = fmaxf(vmax, acc[s][u][r]);
        float vsum = 0.0f;
#pragma unroll
        for (int s = 0; s < 2; s++)
#pragma unroll
            for (int r = 0; r < 16; r++) vsum += __expf(acc[s][u][r] - vmax);
        // combine with partner lane (lane^32) holding the other 16 rows/stripe
        float vmax2 = __shfl_xor(vmax, 32, 64);
        float vsum2 = __shfl_xor(vsum, 32, 64);
        float mc = fmaxf(vmax, vmax2);
        float sc = vsum * __expf(vmax - mc) + vsum2 * __expf(vmax2 - mc);
        if (l5 == 0) {
            size_t pidx = (size_t)(blockIdx.y * 2 + member) * NPIX + m0 + bq + u * 32 + l31;
            pm[pidx] = mc;
            pl[pidx] = sc;
        }
    }
}

// out: relu(x + bias + W.(sum_q Ypq)^T), single batch. grid (32, 4).
// B operand = sum of 4 fp16 K-quarter partials, combined during staging.
__global__ __launch_bounds__(256) void out_mfma(
    const short* __restrict__ wof,
    const float* __restrict__ b_o1, const float* __restrict__ b_o2,
    const short* __restrict__ Yp,
    const float* __restrict__ x, float* __restrict__ out, int b)
{
    __shared__ short LA[128 * AST2], LB[128 * AST2];
    const size_t CN_ = (size_t)NPIX * CC;
    const int ch0 = blockIdx.y * 128;
    const int pix0 = blockIdx.x * 128;
    const int mode = ch0 < 256 ? 0 : 1;
    const short* W = wof + mode * 65536 + (size_t)(ch0 & 255) * 256;
    const short* Yq = Yp + (size_t)mode * 4 * CN_;
    const float* bias = mode == 0 ? b_o1 : b_o2;

    const int t = threadIdx.x, lane = t & 63, w = t >> 6;
    const int l31 = lane & 31, l5 = lane >> 5;
    const int nq = (w & 1) * 64, mq = (w >> 1) * 64;
    const int sr = t >> 1;
    const int sk = (t & 1) * 16;
    const size_t gsA = (size_t)sr * 256 + sk;
    const size_t gsB = (size_t)(pix0 + sr) * 256 + sk;
    const int ls = sr * AST2 + sk;

    f32x16 acc[2][2] = {};

    bf16x8 rA0 = *(const bf16x8*)(W + gsA);
    bf16x8 rA1 = *(const bf16x8*)(W + gsA + 8);
    f16x8 rB0, rB1;
    {
        f16x8 a0 = *(const f16x8*)(Yq + gsB);
        f16x8 a1 = *(const f16x8*)(Yq + CN_ + gsB);
        f16x8 a2 = *(const f16x8*)(Yq + 2 * CN_ + gsB);
        f16x8 a3 = *(const f16x8*)(Yq + 3 * CN_ + gsB);
        rB0 = (a0 + a1) + (a2 + a3);
        f16x8 c0 = *(const f16x8*)(Yq + gsB + 8);
        f16x8 c1 = *(const f16x8*)(Yq + CN_ + gsB + 8);
        f16x8 c2 = *(const f16x8*)(Yq + 2 * CN_ + gsB + 8);
        f16x8 c3 = *(const f16x8*)(Yq + 3 * CN_ + gsB + 8);
        rB1 = (c0 + c1) + (c2 + c3);
    }

    for (int k0 = 0; k0 < 256; k0 += 32) {
        __syncthreads();
        *(bf16x8*)&LA[ls]    = rA0;
        *(bf16x8*)&LA[ls + 8] = rA1;
        *(f16x8*)&LB[ls]     = rB0;
        *(f16x8*)&LB[ls + 8] = rB1;
        __syncthreads();
        if (k0 + 32 < 256) {
            size_t gA = gsA + k0 + 32;
            size_t gB = gsB + k0 + 32;
            rA0 = *(const bf16x8*)(W + gA);
            rA1 = *(const bf16x8*)(W + gA + 8);
            f16x8 a0 = *(const f16x8*)(Yq + gB);
            f16x8 a1 = *(const f16x8*)(Yq + CN_ + gB);
            f16x8 a2 = *(const f16x8*)(Yq + 2 * CN_ + gB);
            f16x8 a3 = *(const f16x8*)(Yq + 3 * CN_ + gB);
            rB0 = (a0 + a1) + (a2 + a3);
            f16x8 c0 = *(const f16x8*)(Yq + gB + 8);
            f16x8 c1 = *(const f16x8*)(Yq + CN_ + gB + 8);
            f16x8 c2 = *(const f16x8*)(Yq + 2 * CN_ + gB + 8);
            f16x8 c3 = *(const f16x8*)(Yq + 3 * CN_ + gB + 8);
            rB1 = (c0 + c1) + (c2 + c3);
        }
#pragma unroll
        for (int ks = 0; ks < 2; ks++) {
            f16x8 a[2], bb[2];
#pragma unroll
            for (int s = 0; s < 2; s++) {
                a[s]  = *(const f16x8*)&LA[(nq + s * 32 + l31) * AST2 + ks * 16 + l5 * 8];
                bb[s] = *(const f16x8*)&LB[(mq + s * 32 + l31) * AST2 + ks * 16 + l5 * 8];
            }
#pragma unroll
            for (int s = 0; s < 2; s++)
#pragma unroll
                for (int u = 0; u < 2; u++)
                    acc[s][u] = __builtin_amdgcn_mfma_f32_32x32x16_f16(a[s], bb[u], acc[s][u], 0, 0, 0);
        }
    }

    const int aq = (w & 1) * 64, bq = (w >> 1) * 64;
#pragma unroll
    for (int s = 0; s < 2; s++)
#pragma unroll
        for (int u = 0; u < 2; u++)
#pragma unroll
            for (int r = 0; r < 16; r++) {
                int ch = ch0 + aq + s * 32 + cdrow(r, l5);
                int pix = pix0 + bq + u * 32 + l31;
                int chm = ch & 255;
                float v = acc[s][u][r] + bias[chm] +
                          x[((size_t)b * CC + chm) * NPIX + pix];
                out[((size_t)b * 2 * CC + ch) * NPIX + pix] = fmaxf(v, 0.0f);
            }
}

// combine 64 col partials. grid (64); 4 chunk-threads per column.
__global__ __launch_bounds__(256) void colstats2_kernel(
    const float* __restrict__ pm, const float* __restrict__ pl,
    float* __restrict__ cm, float* __restrict__ cli)
{
    __shared__ float sm[4][64], sl[4][64];
    const int t = threadIdx.x;
    const int cl = t & 63, ch = t >> 6;
    const int col = blockIdx.x * 64 + cl;
    float m = -1e30f, l = 0.0f;
    for (int i = ch * 16; i < ch * 16 + 16; i++) {
        float m2 = pm[(size_t)i * NPIX + col];
        float l2 = pl[(size_t)i * NPIX + col];
        float mn = fmaxf(m, m2);
        l = l * __expf(m - mn) + l2 * __expf(m2 - mn);
        m = mn;
    }
    sm[ch][cl] = m;
    sl[ch][cl] = l;
    __syncthreads();
    if (ch == 0) {
#pragma unroll
        for (int j = 1; j < 4; j++) {
            float m2 = sm[j][cl], l2 = sl[j][cl];
            float mn = fmaxf(m, m2);
            l = l * __expf(m - mn) + l2 * __expf(m2 - mn);
            m = mn;
        }
        cm[col]  = m;
        cli[col] = 1.0f / l;
    }
}

// ---------------- fused row-stats + P materialization (fp16 P) --------------
// reads int16 S. grid (4096).
__global__ __launch_bounds__(256) void rowexpP_kernel(
    const short* __restrict__ S16,
    const float* __restrict__ colm, const float* __restrict__ colli,
    short* __restrict__ P1, short* __restrict__ P2)
{
    const int row = blockIdx.x;
    const short* sp = S16 + (size_t)row * NPIX;
    const int t = threadIdx.x;
    const int w = t >> 6, lane = t & 63;
    __shared__ float red[4];

    float s4[16];
#pragma unroll
    for (int i = 0; i < 4; i++) {
        short4v v = *(const short4v*)(sp + (i * 256 + t) * 4);
        s4[i * 4 + 0] = s_dec(v.x);
        s4[i * 4 + 1] = s_dec(v.y);
        s4[i * 4 + 2] = s_dec(v.z);
        s4[i * 4 + 3] = s_dec(v.w);
    }

    float m = -1e30f;
#pragma unroll
    for (int i = 0; i < 16; i++) m = fmaxf(m, s4[i]);
    for (int off = 32; off; off >>= 1) m = fmaxf(m, __shfl_xor(m, off, 64));
    if (lane == 0) red[w] = m;
    __syncthreads();
    m = fmaxf(fmaxf(red[0], red[1]), fmaxf(red[2], red[3]));
    __syncthreads();

    float e[16];
    float sum = 0.0f;
#pragma unroll
    for (int i = 0; i < 16; i++) {
        e[i] = __expf(s4[i] - m);
        sum += e[i];
    }
    for (int off = 32; off; off >>= 1) sum += __shfl_xor(sum, off, 64);
    if (lane == 0) red[w] = sum;
    __syncthreads();
    float rl = 1.0f / (red[0] + red[1] + red[2] + red[3]);

    short* p1 = P1 + (size_t)row * NPIX;
    short* p2 = P2 + (size_t)row * NPIX;
#pragma unroll
    for (int i = 0; i < 4; i++) {
        int idx = (i * 256 + t) * 4;
        float4 cm4 = *(const float4*)(colm + idx);
        float4 cl4 = *(const float4*)(colli + idx);
        short4v a, bvv;
        a.x = f2h(e[i * 4 + 0] * rl);
        a.y = f2h(e[i * 4 + 1] * rl);
        a.z = f2h(e[i * 4 + 2] * rl);
        a.w = f2h(e[i * 4 + 3] * rl);
        bvv.x = f2h(__expf(s4[i * 4 + 0] - cm4.x) * cl4.x);
        bvv.y = f2h(__expf(s4[i * 4 + 1] - cm4.y) * cl4.y);
        bvv.z = f2h(__expf(s4[i * 4 + 2] - cm4.z) * cl4.z);
        bvv.w = f2h(__expf(s4[i * 4 + 3] - cm4.w) * cl4.w);
        *(short4v*)(p1 + idx) = a;
        *(short4v*)(p2 + idx) = bvv;
    }
}

// ---------------- Y = P @ Vt^T: K-split fp16 partials ----------------
// grid (64 nT, 4 kq, 2 mode) = 512 blocks (2/CU). Block: 64n x 256c over
// K=1024 (its quarter). P segment read exactly once; Vt L2-hot.
__global__ __launch_bounds__(256) void ygemm_kernel(
    const short* __restrict__ P1, const short* __restrict__ P2,
    const short* __restrict__ Vt, short* __restrict__ Yp)
{
    __shared__ short LA[64 * YST];     //  9216 B
    __shared__ short LB[256 * YST];    // 36864 B
    const int mode = blockIdx.z, kq = blockIdx.y;
    const int n0 = blockIdx.x * 64;
    const short* A = (mode ? P2 : P1) + (size_t)n0 * NPIX;
    const short* B = Vt;
    const int kbase = kq * 1024;

    const int t = threadIdx.x, lane = t & 63, w = t >> 6;
    const int l31 = lane & 31, l5 = lane >> 5;
    const int nst = (w & 1) * 32, cb = (w >> 1) * 128;
    const int ar = t >> 2;            // staging row 0..63
    const int ak = (t & 3) * 16;      // staging k offset (shorts)

    // prologue prefetch (step 0)
    bf16x8 pa[2], pb[8];
    {
        const short* ap = A + (size_t)ar * NPIX + kbase + ak;
        pa[0] = *(const bf16x8*)ap;
        pa[1] = *(const bf16x8*)(ap + 8);
#pragma unroll
        for (int i = 0; i < 4; i++) {
            const short* bp = B + (size_t)(i * 64 + ar) * NPIX + kbase + ak;
            pb[2 * i]     = *(const bf16x8*)bp;
            pb[2 * i + 1] = *(const bf16x8*)(bp + 8);
        }
    }

    f32x16 acc[4] = {};
    for (int s = 0; s < 16; s++) {
        __syncthreads();
        *(bf16x8*)&LA[ar * YST + ak]     = pa[0];
        *(bf16x8*)&LA[ar * YST + ak + 8] = pa[1];
#pragma unroll
        for (int i = 0; i < 4; i++) {
            *(bf16x8*)&LB[(i * 64 + ar) * YST + ak]     = pb[2 * i];
            *(bf16x8*)&LB[(i * 64 + ar) * YST + ak + 8] = pb[2 * i + 1];
        }
        __syncthreads();
        if (s + 1 < 16) {
            int kg = kbase + (s + 1) * 64 + ak;
            const short* ap = A + (size_t)ar * NPIX + kg;
            pa[0] = *(const bf16x8*)ap;
            pa[1] = *(const bf16x8*)(ap + 8);
#pragma unroll
            for (int i = 0; i < 4; i++) {
                const short* bp = B + (size_t)(i * 64 + ar) * NPIX + kg;
                pb[2 * i]     = *(const bf16x8*)bp;
                pb[2 * i + 1] = *(const bf16x8*)(bp + 8);
            }
        }
#pragma unroll
        for (int kc = 0; kc < 4; kc++) {
            f16x8 af = *(const f16x8*)&LA[(nst + l31) * YST + kc * 16 + l5 * 8];
#pragma unroll
            for (int u = 0; u < 4; u++) {
                f16x8 bf = *(const f16x8*)&LB[(cb + u * 32 + l31) * YST + kc * 16 + l5 * 8];
                acc[u] = __builtin_amdgcn_mfma_f32_32x32x16_f16(af, bf, acc[u], 0, 0, 0);
            }
        }
    }

    short* Yo = Yp + (size_t)(mode * 4 + kq) * ((size_t)NPIX * CC);
#pragma unroll
    for (int u = 0; u < 4; u++)
#pragma unroll
        for (int r = 0; r < 16; r++) {
            int rr = cdrow(r, l5);
            Yo[(size_t)(n0 + nst + rr) * CC + cb + u * 32 + l31] = f2h(acc[u][r]);
        }
}

extern "C" void kernel_launch(void* const* d_in, const int* in_sizes, int n_in,
                              void* d_out, int out_size, void* d_ws, size_t ws_size,
                              hipStream_t stream)
{
    (void)in_sizes; (void)n_in; (void)out_size; (void)ws_size;
    const float* x      = (const float*)d_in[0];
    const float* w_teta = (const float*)d_in[1];
    const float* b_teta = (const float*)d_in[2];
    const float* w_fi   = (const float*)d_in[3];
    const float* b_fi   = (const float*)d_in[4];
    const float* w_gi   = (const float*)d_in[5];
    const float* b_gi   = (const float*)d_in[6];
    const float* w_o1   = (const float*)d_in[7];
    const float* b_o1   = (const float*)d_in[8];
    const float* w_o2   = (const float*)d_in[9];
    const float* b_o2   = (const float*)d_in[10];
    float* out = (float*)d_out;

    const size_t CN = (size_t)CC * NPIX;       // 1M elements
    const size_t NN = (size_t)NPIX * NPIX;     // 16.7M
    short* wsp   = (short*)d_ws;
    // --- persistent regions ---
    short* S16   = wsp;                         // 32 MB (int16 scores)
    short* P1    = S16 + NN;                    // 32 MB (fp16)
    short* P2    = P1 + NN;                     // 32 MB (fp16)
    short* Yp    = P2 + NN;                     // 16 MB (8 x 2 MB fp16)
    short* x1f   = Yp + 8 * CN;                 // 8 MB (fp16)
    short* x2tf  = x1f + BB * CN;               // 8 MB (fp16)
    short* Vtb   = x2tf + BB * CN;              // 8 MB (fp16)
    float* cm    = (float*)(Vtb + BB * CN);
    float* cli   = cm + NPIX;
    float* pm    = cli + NPIX;                  // 64*NPIX = 1 MB
    float* pl    = pm + 64 * NPIX;              // 1 MB
    short* wall  = (short*)(pl + 64 * NPIX);    // 5*65536 fp16 weights
    short* wpf   = wall;                        // teta, fi, gi
    short* wof   = wall + 3 * 65536;            // o1, o2
    // --- aliases (pre-phase only; dead before batch loop) ---
    short* xtf  = P1;                           // 8 MB in P1 region
    short* x2f  = P2;                           // 8 MB in P2 region
    short* x3f  = x2f + BB * CN;                // 8 MB in P2 region

    dim3 blk(256);
    pack_w5<<<dim3(64, 5), blk, 0, stream>>>(w_teta, w_fi, w_gi, w_o1, w_o2, wall);
    pack_t_f16<<<dim3(128, 8, 4), blk, 0, stream>>>(x, xtf);

    proj_mfma<<<dim3(32, 2, 12), blk, 0, stream>>>(
        wpf, xtf, b_teta, b_fi, b_gi, x1f, x2f, x3f);

    tr16_cn<<<dim3(128, 8, 4), blk, 0, stream>>>(x2f, x2tf);
    packVt_bf<<<dim3(128, 8, 4), blk, 0, stream>>>(x3f, Vtb);

    for (int b = 0; b < BB; b++) {
        scores_mfma<<<dim3(32, 32), blk, 0, stream>>>(
            x1f + b * CN, x2tf + b * CN, S16, pm, pl);
        colstats2_kernel<<<dim3(64), blk, 0, stream>>>(pm, pl, cm, cli);
        rowexpP_kernel<<<dim3(4096), blk, 0, stream>>>(S16, cm, cli, P1, P2);
        ygemm_kernel<<<dim3(64, 4, 2), blk, 0, stream>>>(
            P1, P2, Vtb + b * CN, Yp);
        out_mfma<<<dim3(32, 4), blk, 0, stream>>>(
            wof, b_o1, b_o2, Yp, x, out, b);
    }
}

// Round 6
// 455.778 us; speedup vs baseline: 1.1986x; 1.0385x over previous
//
#include <hip/hip_runtime.h>

#define BB   4
#define CC   256
#define NPIX 4096
#define AST2 40    // mfma-core LDS row stride (shorts), 80 B, 16B-aligned
#define YST  72    // pv LDS row stride (shorts), 144 B, 16B-aligned

typedef __attribute__((ext_vector_type(8)))  short bf16x8;
typedef __attribute__((ext_vector_type(8)))  _Float16 f16x8;
typedef __attribute__((ext_vector_type(4)))  short short4v;
typedef __attribute__((ext_vector_type(16))) float f32x16;

__device__ __forceinline__ short f2h(float f) {
    _Float16 h = (_Float16)f;           // v_cvt_f16_f32 (RNE)
    return __builtin_bit_cast(short, h);
}
__device__ __forceinline__ int cdrow(int r, int l5) {
    return (r & 3) + 8 * (r >> 2) + 4 * l5;   // verified m74/m101 C/D row map
}
// S fixed-point codec: s in (-128,128), scale 256 -> |err| <= 2^-9
__device__ __forceinline__ short s_enc(float v) {
    float c = fmaxf(fminf(v, 127.9f), -127.9f);
    return (short)__float2int_rn(c * 256.0f);
}
__device__ __forceinline__ float s_dec(short v) {
    return (float)v * (1.0f / 256.0f);
}

// ---------------------------------------------------------------------------
// Single-fp16 MFMA core: 128x128 tile, K=256, register-prefetch pipelined.
// 20 KB LDS.
// ---------------------------------------------------------------------------
__device__ __forceinline__ void mfma_core_f16(
    const short* __restrict__ A, const short* __restrict__ B, f32x16 acc[2][2])
{
    __shared__ short LA[128 * AST2], LB[128 * AST2];
    const int t = threadIdx.x;
    const int lane = t & 63, w = t >> 6;
    const int l31 = lane & 31, l5 = lane >> 5;
    const int nq = (w & 1) * 64, mq = (w >> 1) * 64;
    const int sr = t >> 1;
    const int sk = (t & 1) * 16;
    const size_t gs = (size_t)sr * 256 + sk;
    const int ls = sr * AST2 + sk;

    bf16x8 rA0 = *(const bf16x8*)(A + gs);
    bf16x8 rA1 = *(const bf16x8*)(A + gs + 8);
    bf16x8 rB0 = *(const bf16x8*)(B + gs);
    bf16x8 rB1 = *(const bf16x8*)(B + gs + 8);

    for (int k0 = 0; k0 < 256; k0 += 32) {
        __syncthreads();
        *(bf16x8*)&LA[ls]     = rA0;
        *(bf16x8*)&LA[ls + 8] = rA1;
        *(bf16x8*)&LB[ls]     = rB0;
        *(bf16x8*)&LB[ls + 8] = rB1;
        __syncthreads();
        if (k0 + 32 < 256) {
            size_t g = gs + k0 + 32;
            rA0 = *(const bf16x8*)(A + g);
            rA1 = *(const bf16x8*)(A + g + 8);
            rB0 = *(const bf16x8*)(B + g);
            rB1 = *(const bf16x8*)(B + g + 8);
        }
#pragma unroll
        for (int ks = 0; ks < 2; ks++) {
            f16x8 a[2], b[2];
#pragma unroll
            for (int s = 0; s < 2; s++) {
                a[s] = *(const f16x8*)&LA[(nq + s * 32 + l31) * AST2 + ks * 16 + l5 * 8];
                b[s] = *(const f16x8*)&LB[(mq + s * 32 + l31) * AST2 + ks * 16 + l5 * 8];
            }
#pragma unroll
            for (int s = 0; s < 2; s++)
#pragma unroll
                for (int u = 0; u < 2; u++)
                    acc[s][u] = __builtin_amdgcn_mfma_f32_32x32x16_f16(a[s], b[u], acc[s][u], 0, 0, 0);
        }
    }
}

// ---------------- pack kernels ----------------

// all 5 weights fp32 -> fp16, same layout. grid (64, 5)
__global__ __launch_bounds__(256) void pack_w5(
    const float* __restrict__ w0, const float* __restrict__ w1,
    const float* __restrict__ w2, const float* __restrict__ w3,
    const float* __restrict__ w4, short* __restrict__ wall)
{
    int which = blockIdx.y;
    const float* w = which == 0 ? w0 : which == 1 ? w1 : which == 2 ? w2
                   : which == 3 ? w3 : w4;
    int idx = blockIdx.x * 1024 + threadIdx.x * 4;
    float4 v = *(const float4*)(w + idx);
    short4v h;
    h.x = f2h(v.x); h.y = f2h(v.y); h.z = f2h(v.z); h.w = f2h(v.w);
    *(short4v*)(wall + which * 65536 + idx) = h;
}

// transpose fp32 [c][n] -> single fp16 [n][c]. grid (128,8,4)
__global__ __launch_bounds__(256) void pack_t_f16(
    const float* __restrict__ in, short* __restrict__ o16)
{
    __shared__ short T[32][36];
    const int b  = blockIdx.z;
    const int n0 = blockIdx.x * 32;
    const int c0 = blockIdx.y * 32;
    const float* src = in + (size_t)b * CC * NPIX;
    const int t = threadIdx.x;
    const int r = t >> 3, q = t & 7;
    float4 v = *(const float4*)(src + (size_t)(c0 + r) * NPIX + n0 + q * 4);
    T[q * 4 + 0][r] = f2h(v.x);
    T[q * 4 + 1][r] = f2h(v.y);
    T[q * 4 + 2][r] = f2h(v.z);
    T[q * 4 + 3][r] = f2h(v.w);
    __syncthreads();
    short4v o;
    o.x = T[r][q * 4 + 0];
    o.y = T[r][q * 4 + 1];
    o.z = T[r][q * 4 + 2];
    o.w = T[r][q * 4 + 3];
    size_t oo = (size_t)b * CC * NPIX + (size_t)(n0 + r) * 256 + c0 + q * 4;
    *(short4v*)(o16 + oo) = o;
}

// transpose fp16 [256][4096] -> fp16 [4096][256]. grid (128,8,4)
__global__ __launch_bounds__(256) void tr16_cn(
    const short* __restrict__ in, short* __restrict__ outp)
{
    __shared__ short T[32][33];
    const int b  = blockIdx.z;
    const int n0 = blockIdx.x * 32;
    const int c0 = blockIdx.y * 32;
    const short* src = in + (size_t)b * CC * NPIX;
    short* dst = outp + (size_t)b * CC * NPIX;
    const int t = threadIdx.x;
    const int r = t >> 3, q = t & 7;
    short4v v = *(const short4v*)(src + (size_t)(c0 + r) * NPIX + n0 + q * 4);
    T[q * 4 + 0][r] = v.x;
    T[q * 4 + 1][r] = v.y;
    T[q * 4 + 2][r] = v.z;
    T[q * 4 + 3][r] = v.w;
    __syncthreads();
    short4v o;
    o.x = T[r][q * 4 + 0];
    o.y = T[r][q * 4 + 1];
    o.z = T[r][q * 4 + 2];
    o.w = T[r][q * 4 + 3];
    *(short4v*)(dst + (size_t)(n0 + r) * 256 + c0 + q * 4) = o;
}

// Vt[c][m] = x3f.flat[m*256+c] (already fp16). grid (128,8,4)
__global__ __launch_bounds__(256) void packVt_bf(
    const short* __restrict__ x3f, short* __restrict__ Vt)
{
    __shared__ short T[32][33];
    const int b  = blockIdx.z;
    const int m0 = blockIdx.x * 32;
    const int c0 = blockIdx.y * 32;
    const short* in = x3f + (size_t)b * CC * NPIX;
    short* out = Vt + (size_t)b * CC * NPIX;
    const int t = threadIdx.x;
    const int r = t >> 3, q = t & 7;
    short4v v = *(const short4v*)(in + (size_t)(m0 + r) * CC + c0 + q * 4);
    T[q * 4 + 0][r] = v.x;
    T[q * 4 + 1][r] = v.y;
    T[q * 4 + 2][r] = v.z;
    T[q * 4 + 3][r] = v.w;
    __syncthreads();
    short4v o;
    o.x = T[r][q * 4 + 0];
    o.y = T[r][q * 4 + 1];
    o.z = T[r][q * 4 + 2];
    o.w = T[r][q * 4 + 3];
    *(short4v*)(out + (size_t)(c0 + r) * NPIX + m0 + q * 4) = o;
}

// ---------------- GEMM kernels ----------------

// proj. grid (32, 2, 12). p=0 -> x1, p=1 -> x2, p=2 -> x3; all fp16 [c][n].
__global__ __launch_bounds__(256) void proj_mfma(
    const short* __restrict__ wpf, const short* __restrict__ xtf,
    const float* __restrict__ b_teta, const float* __restrict__ b_fi,
    const float* __restrict__ b_gi,
    short* __restrict__ x1f, short* __restrict__ x2f, short* __restrict__ x3f)
{
    const int z = blockIdx.z, p = z >> 2, b = z & 3;
    const int n0 = blockIdx.x * 128, c0 = blockIdx.y * 128;
    const size_t CN = (size_t)CC * NPIX;
    const short* Ah = wpf + p * 65536 + c0 * 256;
    const short* Bh = xtf + (size_t)b * CN + (size_t)n0 * 256;
    const float* bias = p == 0 ? b_teta : p == 1 ? b_fi : b_gi;
    short* dst = p == 0 ? x1f : p == 1 ? x2f : x3f;

    f32x16 acc[2][2] = {};
    mfma_core_f16(Ah, Bh, acc);

    const int t = threadIdx.x, lane = t & 63, w = t >> 6;
    const int l31 = lane & 31, l5 = lane >> 5;
    const int aq = (w & 1) * 64, bq = (w >> 1) * 64;
#pragma unroll
    for (int s = 0; s < 2; s++)
#pragma unroll
        for (int u = 0; u < 2; u++)
#pragma unroll
            for (int r = 0; r < 16; r++) {
                int c = c0 + aq + s * 32 + cdrow(r, l5);
                int n = n0 + bq + u * 32 + l31;
                float v = acc[s][u][r] + bias[c];
                size_t o = (size_t)b * CN + (size_t)c * NPIX + n;
                dst[o] = f2h(v);
            }
}

// scores + fused column partial stats. S stored int16 fixed-point (x256).
// grid (32, 32) per batch.
__global__ __launch_bounds__(256) void scores_mfma(
    const short* __restrict__ x1f, const short* __restrict__ x2tf,
    short* __restrict__ S16, float* __restrict__ pm, float* __restrict__ pl)
{
    const int m0 = blockIdx.x * 128, n0 = blockIdx.y * 128;
    f32x16 acc[2][2] = {};
    mfma_core_f16(x1f + (size_t)n0 * 256, x2tf + (size_t)m0 * 256, acc);

    const int t = threadIdx.x, lane = t & 63, w = t >> 6;
    const int l31 = lane & 31, l5 = lane >> 5;
    const int aq = (w & 1) * 64, bq = (w >> 1) * 64;
#pragma unroll
    for (int s = 0; s < 2; s++)
#pragma unroll
        for (int u = 0; u < 2; u++)
#pragma unroll
            for (int r = 0; r < 16; r++) {
                int n = n0 + aq + s * 32 + cdrow(r, l5);
                int m = m0 + bq + u * 32 + l31;
                S16[(size_t)n * NPIX + m] = s_enc(acc[s][u][r]);
            }

    // column partial stats over this block's 64-row half (member = w&1).
    const int member = w & 1;
#pragma unroll
    for (int u = 0; u < 2; u++) {
        float vmax = -1e30f;
#pragma unroll
        for (int s = 0; s < 2; s++)
#pragma unroll
            for (int r = 0; r < 16; r++) vmax = fmaxf(vmax, acc[s][u][r]);
        float vsum = 0.0f;
#pragma unroll
        for (int s = 0; s < 2; s++)
#pragma unroll
            for (int r = 0; r < 16; r++) vsum += __expf(acc[s][u][r] - vmax);
        // combine with partner lane (lane^32) holding the other 16 rows/stripe
        float vmax2 = __shfl_xor(vmax, 32, 64);
        float vsum2 = __shfl_xor(vsum, 32, 64);
        float mc = fmaxf(vmax, vmax2);
        float sc = vsum * __expf(vmax - mc) + vsum2 * __expf(vmax2 - mc);
        if (l5 == 0) {
            size_t pidx = (size_t)(blockIdx.y * 2 + member) * NPIX + m0 + bq + u * 32 + l31;
            pm[pidx] = mc;
            pl[pidx] = sc;
        }
    }
}

// out: relu(x + bias + W.(sum_q Ypq)^T), single batch. grid (32, 4).
// B operand = sum of 4 fp16 K-quarter partials, combined during staging.
__global__ __launch_bounds__(256) void out_mfma(
    const short* __restrict__ wof,
    const float* __restrict__ b_o1, const float* __restrict__ b_o2,
    const short* __restrict__ Yp,
    const float* __restrict__ x, float* __restrict__ out, int b)
{
    __shared__ short LA[128 * AST2], LB[128 * AST2];
    const size_t CN_ = (size_t)NPIX * CC;
    const int ch0 = blockIdx.y * 128;
    const int pix0 = blockIdx.x * 128;
    const int mode = ch0 < 256 ? 0 : 1;
    const short* W = wof + mode * 65536 + (size_t)(ch0 & 255) * 256;
    const short* Yq = Yp + (size_t)mode * 4 * CN_;
    const float* bias = mode == 0 ? b_o1 : b_o2;

    const int t = threadIdx.x, lane = t & 63, w = t >> 6;
    const int l31 = lane & 31, l5 = lane >> 5;
    const int nq = (w & 1) * 64, mq = (w >> 1) * 64;
    const int sr = t >> 1;
    const int sk = (t & 1) * 16;
    const size_t gsA = (size_t)sr * 256 + sk;
    const size_t gsB = (size_t)(pix0 + sr) * 256 + sk;
    const int ls = sr * AST2 + sk;

    f32x16 acc[2][2] = {};

    bf16x8 rA0 = *(const bf16x8*)(W + gsA);
    bf16x8 rA1 = *(const bf16x8*)(W + gsA + 8);
    f16x8 rB0, rB1;
    {
        f16x8 a0 = *(const f16x8*)(Yq + gsB);
        f16x8 a1 = *(const f16x8*)(Yq + CN_ + gsB);
        f16x8 a2 = *(const f16x8*)(Yq + 2 * CN_ + gsB);
        f16x8 a3 = *(const f16x8*)(Yq + 3 * CN_ + gsB);
        rB0 = (a0 + a1) + (a2 + a3);
        f16x8 c0 = *(const f16x8*)(Yq + gsB + 8);
        f16x8 c1 = *(const f16x8*)(Yq + CN_ + gsB + 8);
        f16x8 c2 = *(const f16x8*)(Yq + 2 * CN_ + gsB + 8);
        f16x8 c3 = *(const f16x8*)(Yq + 3 * CN_ + gsB + 8);
        rB1 = (c0 + c1) + (c2 + c3);
    }

    for (int k0 = 0; k0 < 256; k0 += 32) {
        __syncthreads();
        *(bf16x8*)&LA[ls]    = rA0;
        *(bf16x8*)&LA[ls + 8] = rA1;
        *(f16x8*)&LB[ls]     = rB0;
        *(f16x8*)&LB[ls + 8] = rB1;
        __syncthreads();
        if (k0 + 32 < 256) {
            size_t gA = gsA + k0 + 32;
            size_t gB = gsB + k0 + 32;
            rA0 = *(const bf16x8*)(W + gA);
            rA1 = *(const bf16x8*)(W + gA + 8);
            f16x8 a0 = *(const f16x8*)(Yq + gB);
            f16x8 a1 = *(const f16x8*)(Yq + CN_ + gB);
            f16x8 a2 = *(const f16x8*)(Yq + 2 * CN_ + gB);
            f16x8 a3 = *(const f16x8*)(Yq + 3 * CN_ + gB);
            rB0 = (a0 + a1) + (a2 + a3);
            f16x8 c0 = *(const f16x8*)(Yq + gB + 8);
            f16x8 c1 = *(const f16x8*)(Yq + CN_ + gB + 8);
            f16x8 c2 = *(const f16x8*)(Yq + 2 * CN_ + gB + 8);
            f16x8 c3 = *(const f16x8*)(Yq + 3 * CN_ + gB + 8);
            rB1 = (c0 + c1) + (c2 + c3);
        }
#pragma unroll
        for (int ks = 0; ks < 2; ks++) {
            f16x8 a[2], bb[2];
#pragma unroll
            for (int s = 0; s < 2; s++) {
                a[s]  = *(const f16x8*)&LA[(nq + s * 32 + l31) * AST2 + ks * 16 + l5 * 8];
                bb[s] = *(const f16x8*)&LB[(mq + s * 32 + l31) * AST2 + ks * 16 + l5 * 8];
            }
#pragma unroll
            for (int s = 0; s < 2; s++)
#pragma unroll
                for (int u = 0; u < 2; u++)
                    acc[s][u] = __builtin_amdgcn_mfma_f32_32x32x16_f16(a[s], bb[u], acc[s][u], 0, 0, 0);
        }
    }

    const int aq = (w & 1) * 64, bq = (w >> 1) * 64;
#pragma unroll
    for (int s = 0; s < 2; s++)
#pragma unroll
        for (int u = 0; u < 2; u++)
#pragma unroll
            for (int r = 0; r < 16; r++) {
                int ch = ch0 + aq + s * 32 + cdrow(r, l5);
                int pix = pix0 + bq + u * 32 + l31;
                int chm = ch & 255;
                float v = acc[s][u][r] + bias[chm] +
                          x[((size_t)b * CC + chm) * NPIX + pix];
                out[((size_t)b * 2 * CC + ch) * NPIX + pix] = fmaxf(v, 0.0f);
            }
}

// stats: blocks [0,64) combine 64 col partials -> cm/cli;
//        blocks [64,4160) reduce one S16 row -> rm/rli.
__global__ __launch_bounds__(256) void stats16_kernel(
    const short* __restrict__ S16,
    const float* __restrict__ pm, const float* __restrict__ pl,
    float* __restrict__ cm, float* __restrict__ cli,
    float* __restrict__ rm, float* __restrict__ rli)
{
    __shared__ float sm[4][64], sl[4][64];
    __shared__ float red[4];
    const int t = threadIdx.x;
    if (blockIdx.x < 64) {
        const int cl = t & 63, ch = t >> 6;
        const int col = blockIdx.x * 64 + cl;
        float m = -1e30f, l = 0.0f;
        for (int i = ch * 16; i < ch * 16 + 16; i++) {
            float m2 = pm[(size_t)i * NPIX + col];
            float l2 = pl[(size_t)i * NPIX + col];
            float mn = fmaxf(m, m2);
            l = l * __expf(m - mn) + l2 * __expf(m2 - mn);
            m = mn;
        }
        sm[ch][cl] = m;
        sl[ch][cl] = l;
        __syncthreads();
        if (ch == 0) {
#pragma unroll
            for (int j = 1; j < 4; j++) {
                float m2 = sm[j][cl], l2 = sl[j][cl];
                float mn = fmaxf(m, m2);
                l = l * __expf(m - mn) + l2 * __expf(m2 - mn);
                m = mn;
            }
            cm[col]  = m;
            cli[col] = 1.0f / l;
        }
    } else {
        const int row = blockIdx.x - 64;
        const short* sp = S16 + (size_t)row * NPIX;
        const int w = t >> 6, lane = t & 63;
        float s4[16];
#pragma unroll
        for (int i = 0; i < 4; i++) {
            short4v v = *(const short4v*)(sp + (i * 256 + t) * 4);
            s4[i * 4 + 0] = s_dec(v.x);
            s4[i * 4 + 1] = s_dec(v.y);
            s4[i * 4 + 2] = s_dec(v.z);
            s4[i * 4 + 3] = s_dec(v.w);
        }
        float m = -1e30f;
#pragma unroll
        for (int i = 0; i < 16; i++) m = fmaxf(m, s4[i]);
        for (int off = 32; off; off >>= 1) m = fmaxf(m, __shfl_xor(m, off, 64));
        if (lane == 0) red[w] = m;
        __syncthreads();
        m = fmaxf(fmaxf(red[0], red[1]), fmaxf(red[2], red[3]));
        __syncthreads();
        float sum = 0.0f;
#pragma unroll
        for (int i = 0; i < 16; i++) sum += __expf(s4[i] - m);
        for (int off = 32; off; off >>= 1) sum += __shfl_xor(sum, off, 64);
        if (lane == 0) red[w] = sum;
        __syncthreads();
        if (t == 0) {
            rm[row]  = m;
            rli[row] = 1.0f / (red[0] + red[1] + red[2] + red[3]);
        }
    }
}

// ---------------- pv: on-the-fly P from int16 S, Yp = P @ Vt^T --------------
// grid (64 nT, 4 kq, 2 mode) = 512 blocks (2/CU). Block: 64n x 256c over
// K=1024 (its quarter). S16 read directly (L3-hot); P never materialized.
__global__ __launch_bounds__(256) void pv_kernel(
    const short* __restrict__ S16, const short* __restrict__ Vt,
    const float* __restrict__ rmv, const float* __restrict__ rliv,
    const float* __restrict__ cmv, const float* __restrict__ cliv,
    short* __restrict__ Yp)
{
    __shared__ short LA[64 * YST];     //  9216 B
    __shared__ short LB[256 * YST];    // 36864 B
    const int mode = blockIdx.z, kq = blockIdx.y;
    const int n0 = blockIdx.x * 64;
    const int kbase = kq * 1024;

    const int t = threadIdx.x, lane = t & 63, w = t >> 6;
    const int l31 = lane & 31, l5 = lane >> 5;
    const int nst = (w & 1) * 32, cb = (w >> 1) * 128;
    const int ar = t >> 2;            // staging row 0..63
    const int ak = (t & 3) * 16;      // staging k offset (16 m values)

    const float mrow = rmv[n0 + ar];
    const float lrow = rliv[n0 + ar];
    const short* sp = S16 + (size_t)(n0 + ar) * NPIX + kbase + ak;

    // prologue prefetch (step 0)
    short4v sv[4];
    bf16x8 pb[8];
#pragma unroll
    for (int i = 0; i < 4; i++)
        sv[i] = *(const short4v*)(sp + i * 4);
#pragma unroll
    for (int i = 0; i < 4; i++) {
        const short* bp = Vt + (size_t)(i * 64 + ar) * NPIX + kbase + ak;
        pb[2 * i]     = *(const bf16x8*)bp;
        pb[2 * i + 1] = *(const bf16x8*)(bp + 8);
    }

    f32x16 acc[4] = {};
    for (int s = 0; s < 16; s++) {
        // compute fp16 P fragment for this step (registers; pre-barrier)
        short4v ph[4];
        if (mode == 0) {
#pragma unroll
            for (int i = 0; i < 4; i++) {
                ph[i].x = f2h(__expf(s_dec(sv[i].x) - mrow) * lrow);
                ph[i].y = f2h(__expf(s_dec(sv[i].y) - mrow) * lrow);
                ph[i].z = f2h(__expf(s_dec(sv[i].z) - mrow) * lrow);
                ph[i].w = f2h(__expf(s_dec(sv[i].w) - mrow) * lrow);
            }
        } else {
            const int mg = kbase + s * 64 + ak;
#pragma unroll
            for (int i = 0; i < 4; i++) {
                float4 cm4 = *(const float4*)(cmv + mg + i * 4);
                float4 cl4 = *(const float4*)(cliv + mg + i * 4);
                ph[i].x = f2h(__expf(s_dec(sv[i].x) - cm4.x) * cl4.x);
                ph[i].y = f2h(__expf(s_dec(sv[i].y) - cm4.y) * cl4.y);
                ph[i].z = f2h(__expf(s_dec(sv[i].z) - cm4.z) * cl4.z);
                ph[i].w = f2h(__expf(s_dec(sv[i].w) - cm4.w) * cl4.w);
            }
        }
        __syncthreads();
#pragma unroll
        for (int i = 0; i < 4; i++)
            *(short4v*)&LA[ar * YST + ak + i * 4] = ph[i];
#pragma unroll
        for (int i = 0; i < 4; i++) {
            *(bf16x8*)&LB[(i * 64 + ar) * YST + ak]     = pb[2 * i];
            *(bf16x8*)&LB[(i * 64 + ar) * YST + ak + 8] = pb[2 * i + 1];
        }
        __syncthreads();
        if (s + 1 < 16) {
            const short* spn = sp + (s + 1) * 64;
#pragma unroll
            for (int i = 0; i < 4; i++)
                sv[i] = *(const short4v*)(spn + i * 4);
            int kg = kbase + (s + 1) * 64 + ak;
#pragma unroll
            for (int i = 0; i < 4; i++) {
                const short* bp = Vt + (size_t)(i * 64 + ar) * NPIX + kg;
                pb[2 * i]     = *(const bf16x8*)bp;
                pb[2 * i + 1] = *(const bf16x8*)(bp + 8);
            }
        }
#pragma unroll
        for (int kc = 0; kc < 4; kc++) {
            f16x8 af = *(const f16x8*)&LA[(nst + l31) * YST + kc * 16 + l5 * 8];
#pragma unroll
            for (int u = 0; u < 4; u++) {
                f16x8 bf = *(const f16x8*)&LB[(cb + u * 32 + l31) * YST + kc * 16 + l5 * 8];
                acc[u] = __builtin_amdgcn_mfma_f32_32x32x16_f16(af, bf, acc[u], 0, 0, 0);
            }
        }
    }

    short* Yo = Yp + (size_t)(mode * 4 + kq) * ((size_t)NPIX * CC);
#pragma unroll
    for (int u = 0; u < 4; u++)
#pragma unroll
        for (int r = 0; r < 16; r++) {
            int rr = cdrow(r, l5);
            Yo[(size_t)(n0 + nst + rr) * CC + cb + u * 32 + l31] = f2h(acc[u][r]);
        }
}

extern "C" void kernel_launch(void* const* d_in, const int* in_sizes, int n_in,
                              void* d_out, int out_size, void* d_ws, size_t ws_size,
                              hipStream_t stream)
{
    (void)in_sizes; (void)n_in; (void)out_size; (void)ws_size;
    const float* x      = (const float*)d_in[0];
    const float* w_teta = (const float*)d_in[1];
    const float* b_teta = (const float*)d_in[2];
    const float* w_fi   = (const float*)d_in[3];
    const float* b_fi   = (const float*)d_in[4];
    const float* w_gi   = (const float*)d_in[5];
    const float* b_gi   = (const float*)d_in[6];
    const float* w_o1   = (const float*)d_in[7];
    const float* b_o1   = (const float*)d_in[8];
    const float* w_o2   = (const float*)d_in[9];
    const float* b_o2   = (const float*)d_in[10];
    float* out = (float*)d_out;

    const size_t CN = (size_t)CC * NPIX;       // 1M elements
    const size_t NN = (size_t)NPIX * NPIX;     // 16.7M
    short* wsp   = (short*)d_ws;
    // --- persistent regions (~75 MB total) ---
    short* S16   = wsp;                         // 32 MB (int16 scores)
    short* Yp    = S16 + NN;                    // 16 MB (8 x 2 MB fp16)
    short* x1f   = Yp + 8 * CN;                 // 8 MB (fp16)
    short* x2tf  = x1f + BB * CN;               // 8 MB (fp16)
    short* Vtb   = x2tf + BB * CN;              // 8 MB (fp16)
    float* cm    = (float*)(Vtb + BB * CN);
    float* cli   = cm + NPIX;
    float* rm    = cli + NPIX;
    float* rli   = rm + NPIX;
    float* pm    = rli + NPIX;                  // 64*NPIX = 1 MB
    float* pl    = pm + 64 * NPIX;              // 1 MB
    short* wall  = (short*)(pl + 64 * NPIX);    // 5*65536 fp16 weights
    short* wpf   = wall;                        // teta, fi, gi
    short* wof   = wall + 3 * 65536;            // o1, o2
    // --- aliases (pre-phase only; dead before batch loop) ---
    short* xtf  = Yp;                           // 8 MB in Yp region
    short* x2f  = S16;                          // 8 MB in S16 region
    short* x3f  = S16 + BB * CN;                // 8 MB in S16 region

    dim3 blk(256);
    pack_w5<<<dim3(64, 5), blk, 0, stream>>>(w_teta, w_fi, w_gi, w_o1, w_o2, wall);
    pack_t_f16<<<dim3(128, 8, 4), blk, 0, stream>>>(x, xtf);

    proj_mfma<<<dim3(32, 2, 12), blk, 0, stream>>>(
        wpf, xtf, b_teta, b_fi, b_gi, x1f, x2f, x3f);

    tr16_cn<<<dim3(128, 8, 4), blk, 0, stream>>>(x2f, x2tf);
    packVt_bf<<<dim3(128, 8, 4), blk, 0, stream>>>(x3f, Vtb);

    for (int b = 0; b < BB; b++) {
        scores_mfma<<<dim3(32, 32), blk, 0, stream>>>(
            x1f + b * CN, x2tf + b * CN, S16, pm, pl);
        stats16_kernel<<<dim3(64 + NPIX), blk, 0, stream>>>(
            S16, pm, pl, cm, cli, rm, rli);
        pv_kernel<<<dim3(64, 4, 2), blk, 0, stream>>>(
            S16, Vtb + b * CN, rm, rli, cm, cli, Yp);
        out_mfma<<<dim3(32, 4), blk, 0, stream>>>(
            wof, b_o1, b_o2, Yp, x, out, b);
    }
}